// Round 3
// baseline (491.671 us; speedup 1.0000x reference)
//
#include <hip/hip_runtime.h>

#define B_  32
#define C_  384
#define HW_ 784
#define N_  25088   // B_*HW_
#define K_  2048
#define MT  112     // rows per fused block; 112*224 = 25088; 112 | 784

#define OFF_F    0
#define OFF_Q    9633792
#define OFF_ASG  19267584
#define OFF_DIST 70647808

#define MARGIN 0.02f

typedef unsigned short u16;
typedef unsigned long long u64;
typedef __attribute__((ext_vector_type(8))) short short8;
typedef __attribute__((ext_vector_type(4))) float floatx4;

static __device__ __forceinline__ u16 f2bf(float x) {
    unsigned u = __builtin_bit_cast(unsigned, x);
    unsigned r = (u + 0x7FFFu + ((u >> 16) & 1u)) >> 16;
    return (u16)r;
}

static __device__ __forceinline__ void gload_lds16(const void* g, void* l) {
    __builtin_amdgcn_global_load_lds(
        (const __attribute__((address_space(1))) unsigned int*)g,
        (__attribute__((address_space(3))) unsigned int*)l,
        16, 0, 0);
}

// ---------------- K1: normalize codebook -> code_n (fp32, ws) + b_hi (bf16, ws) ----------------
__global__ __launch_bounds__(256) void k_code(const float* __restrict__ cb,
                                              float* __restrict__ code_n,
                                              u16* __restrict__ b_hi) {
    int row  = blockIdx.x * 4 + (threadIdx.x >> 6);
    int lane = threadIdx.x & 63;
    const float* src = cb + (size_t)row * C_;
    float v[6];
    float ss = 0.f;
#pragma unroll
    for (int i = 0; i < 6; ++i) { v[i] = src[lane + 64 * i]; ss += v[i] * v[i]; }
#pragma unroll
    for (int off = 32; off; off >>= 1) ss += __shfl_xor(ss, off, 64);
    float inv = 1.f / fmaxf(sqrtf(ss), 1e-12f);
#pragma unroll
    for (int i = 0; i < 6; ++i) {
        float vn = v[i] * inv;
        code_n[(size_t)row * C_ + lane + 64 * i] = vn;
        b_hi  [(size_t)row * C_ + lane + 64 * i] = f2bf(vn);
    }
}

// ---------------- K2: feat -> f (N,C), inv_n (ws), a_hi (bf16, stashed in dist rows) ----------------
// a_hi row n lives in the first 384 u16 of dist row n (stride 4096 u16 = 2048 floats)
__global__ __launch_bounds__(256) void k_prep(const float* __restrict__ feat,
                                              float* __restrict__ f_out,
                                              float* __restrict__ inv_n,
                                              u16* a_hi) {
    __shared__ float tile[C_][17];
    __shared__ float red[16][17];
    __shared__ float s_inv[16];
    int b   = blockIdx.y;
    int hw0 = blockIdx.x * 16;
    int tid = threadIdx.x;
    int px  = tid & 15, cq = tid >> 4;

#pragma unroll
    for (int it = 0; it < 24; ++it) {
        int c = cq + 16 * it;
        tile[c][px] = feat[((size_t)(b * C_ + c)) * HW_ + hw0 + px];
    }
    __syncthreads();
    float ss = 0.f;
#pragma unroll
    for (int q = 0; q < 24; ++q) {
        float v = tile[cq + 16 * q][px];
        ss = fmaf(v, v, ss);
    }
    red[cq][px] = ss;
    __syncthreads();
    if (tid < 16) {
        float tot = 0.f;
#pragma unroll
        for (int p = 0; p < 16; ++p) tot += red[p][tid];
        float inv = 1.f / fmaxf(sqrtf(tot), 1e-12f);
        s_inv[tid] = inv;
        inv_n[(size_t)b * HW_ + hw0 + tid] = inv;
    }
    __syncthreads();

    // f (N,C layout)
    {
        int p2 = tid >> 4, cc = tid & 15;
        size_t nbase = ((size_t)(b * HW_ + hw0 + p2)) * C_;
#pragma unroll
        for (int it = 0; it < 24; ++it) {
            int c = cc + 16 * it;
            f_out[nbase + c] = tile[c][p2];
        }
    }
    // a_hi (normalized bf16, packed u32) into dist rows
    {
        int p2 = tid >> 4, cc = tid & 15;
        float inv = s_inv[p2];
        u16* aptr = a_hi + ((size_t)(b * HW_ + hw0 + p2)) * 4096;
#pragma unroll
        for (int it = 0; it < 12; ++it) {
            int c0 = 2 * cc + 32 * it;
            u16 h0 = f2bf(tile[c0][p2] * inv);
            u16 h1 = f2bf(tile[c0 + 1][p2] * inv);
            *(unsigned*)(aptr + c0) = (unsigned)h0 | ((unsigned)h1 << 16);
        }
    }
}

// ---------------- K3: fused GEMM + stats + assignment + q ----------------
#define STAGE_B(p, it_, t_)                                                       \
    {                                                                             \
        _Pragma("unroll")                                                         \
        for (int g = 0; g < 4; ++g) {                                             \
            int v = g * 256 + tid;                                                \
            int row = v >> 2, sp = v & 3;                                         \
            int fs = (row ^ (row >> 2)) & 3;                                      \
            gload_lds16(bHi + (size_t)((it_) * 256 + row) * C_ + (t_) * 32 + 8 * (sp ^ fs), \
                        sB[p] + v * 16);                                          \
        }                                                                         \
    }

__global__ __launch_bounds__(256, 1) void k_fused(
    const u16* __restrict__ bHi, const float* __restrict__ codeN,
    const float* __restrict__ invN, const float* __restrict__ feat,
    float* dist, float* __restrict__ asg, float* __restrict__ qOut) {

    __shared__ __align__(16) char sA[12 * MT * 64];   // 86016 B; aliased as cbuf later
    __shared__ __align__(16) char sB[2][256 * 64];    // 32768 B
    __shared__ float s_wsum[4][MT];
    __shared__ u64   s_wmin[4][MT];
    __shared__ float s_inv[MT], s_dmin[MT];
    __shared__ int   s_amin[MT], s_cnt[MT], s_cand[MT][16];

    const int tid = threadIdx.x;
    const int n0  = blockIdx.x * MT;
    const int b   = n0 / HW_;
    const int hw0 = n0 - b * HW_;
    const int w   = tid >> 6, l = tid & 63;
    const int q4  = l >> 4, r15 = l & 15;
    const int wn  = w * 64;

    const u16* aHi = (const u16*)dist;   // a_hi rows at stride 4096 u16

    // ---- stage A: 12 chunks of [112 rows][32 k] ----
#pragma unroll 1
    for (int ch = 0; ch < 12; ++ch) {
        for (int v = tid; v < MT * 4; v += 256) {
            int row = v >> 2, sp = v & 3;
            int fs = (row ^ (row >> 2)) & 3;
            gload_lds16(aHi + (size_t)(n0 + row) * 4096 + ch * 32 + 8 * (sp ^ fs),
                        sA + ch * (MT * 64) + v * 16);
        }
    }
    STAGE_B(0, 0, 0);
    if (tid < MT) {
        s_wsum[0][tid] = s_wsum[1][tid] = s_wsum[2][tid] = s_wsum[3][tid] = 0.f;
        s_wmin[0][tid] = s_wmin[1][tid] = s_wmin[2][tid] = s_wmin[3][tid] = ~0ull;
        s_cnt[tid] = 0;
    }
    __syncthreads();

    floatx4 acc[7][4];
#pragma unroll
    for (int i = 0; i < 7; ++i)
#pragma unroll
        for (int j = 0; j < 4; ++j) acc[i][j] = (floatx4)0.f;

    const int slot = (q4 ^ ((r15 ^ (r15 >> 2)) & 3)) << 4;

#pragma unroll 1
    for (int c = 0; c < 96; ++c) {
        int p = c & 1;
        if (c < 95) {
            int cn = c + 1;
            STAGE_B(cn & 1, cn / 12, cn % 12);
        }
        const char* Ab = sA + (c % 12) * (MT * 64);
        const char* Bb = sB[p];
        short8 af[7], bf[4];
#pragma unroll
        for (int i = 0; i < 7; ++i)
            af[i] = *(const short8*)(Ab + (i * 16 + r15) * 64 + slot);
#pragma unroll
        for (int j = 0; j < 4; ++j)
            bf[j] = *(const short8*)(Bb + (wn + j * 16 + r15) * 64 + slot);
#pragma unroll
        for (int i = 0; i < 7; ++i)
#pragma unroll
            for (int j = 0; j < 4; ++j)
                acc[i][j] = __builtin_amdgcn_mfma_f32_16x16x32_bf16(af[i], bf[j], acc[i][j], 0, 0, 0);

        if ((c % 12) == 11) {
            int iter = c / 12;
#pragma unroll
            for (int i = 0; i < 7; ++i) {
#pragma unroll
                for (int rr = 0; rr < 4; ++rr) {
                    int row = i * 16 + q4 * 4 + rr;
                    float esum = 0.f;
                    u64 mk = ~0ull;
#pragma unroll
                    for (int j = 0; j < 4; ++j) {
                        float d = 2.f - 2.f * acc[i][j][rr];
                        int col = iter * 256 + wn + j * 16 + r15;
                        dist[(size_t)(n0 + row) * K_ + col] = d;
                        esum += __expf(-10.f * d);
                        unsigned bits = __builtin_bit_cast(unsigned, d);
                        unsigned key = bits ^ (unsigned)(((int)bits >> 31) | (int)0x80000000);
                        u64 pk = ((u64)key << 32) | (unsigned)col;
                        mk = pk < mk ? pk : mk;
                    }
#pragma unroll
                    for (int off = 1; off < 16; off <<= 1) {
                        esum += __shfl_xor(esum, off, 64);
                        u64 om = __shfl_xor(mk, off, 64);
                        mk = om < mk ? om : mk;
                    }
                    if (r15 == 0) {
                        s_wsum[w][row] += esum;
                        u64 cur = s_wmin[w][row];
                        s_wmin[w][row] = mk < cur ? mk : cur;
                    }
                }
#pragma unroll
                for (int j = 0; j < 4; ++j) acc[i][j] = (floatx4)0.f;
            }
        }
        __syncthreads();
    }

    // ---- combine per-wave stats ----
    if (tid < MT) {
        float s = s_wsum[0][tid] + s_wsum[1][tid] + s_wsum[2][tid] + s_wsum[3][tid];
        u64 m = s_wmin[0][tid];
        if (s_wmin[1][tid] < m) m = s_wmin[1][tid];
        if (s_wmin[2][tid] < m) m = s_wmin[2][tid];
        if (s_wmin[3][tid] < m) m = s_wmin[3][tid];
        s_inv[tid]  = 1.f / s;
        unsigned key = (unsigned)(m >> 32);
        unsigned bits = (key & 0x80000000u) ? (key ^ 0x80000000u) : ~key;
        s_dmin[tid] = __builtin_bit_cast(float, bits);
        s_amin[tid] = (int)(m & 0xffffffffu);
    }
    __syncthreads();

    // ---- assignment: re-read own dist tile, transpose via LDS, collect candidates ----
    float* cbf = (float*)sA;                 // [2][64][113] fp32 = 57856 B
    const int px = tid & 127, kg = tid >> 7;
    const int k16 = tid & 15, rg = tid >> 4;
#pragma unroll 1
    for (int chk = 0; chk < 32; ++chk) {
        int k0 = chk * 64;
        float* cbp = cbf + (chk & 1) * (64 * 113);
#pragma unroll
        for (int rr = 0; rr < 7; ++rr) {
            int r = rg + 16 * rr;
            float4 dv = *(const float4*)(dist + (size_t)(n0 + r) * K_ + k0 + 4 * k16);
            float inv = s_inv[r], dthr = s_dmin[r] + MARGIN;
            float dd[4] = {dv.x, dv.y, dv.z, dv.w};
#pragma unroll
            for (int cc = 0; cc < 4; ++cc) {
                cbp[(4 * k16 + cc) * 113 + r] = __expf(-10.f * dd[cc]) * inv;
                if (dd[cc] <= dthr) {
                    int idx = atomicAdd(&s_cnt[r], 1);
                    if (idx < 16) s_cand[r][idx] = k0 + 4 * k16 + cc;
                }
            }
        }
        __syncthreads();
        if (px < MT) {
            size_t base = ((size_t)b * K_ + k0 + kg * 32) * HW_ + hw0 + px;
            const float* src = cbp + (kg * 32) * 113 + px;
#pragma unroll
            for (int ki = 0; ki < 32; ++ki)
                asg[base + (size_t)ki * HW_] = src[ki * 113];
        }
    }
    __syncthreads();

    // ---- exact fp32 recheck for ambiguous rows (one wave per row) ----
#pragma unroll 1
    for (int r = w; r < MT; r += 4) {
        int cnt = s_cnt[r];
        if (cnt < 2) continue;
        cnt = cnt > 16 ? 16 : cnt;
        float ivn = invN[n0 + r];
        float fv[6];
#pragma unroll
        for (int ii = 0; ii < 6; ++ii)
            fv[ii] = feat[((size_t)b * C_ + l + 64 * ii) * HW_ + hw0 + r] * ivn;
        int kbest = s_amin[r];
        float dbest;
        {
            float dt = 0.f;
            const float* cr = codeN + (size_t)kbest * C_;
#pragma unroll
            for (int ii = 0; ii < 6; ++ii) dt = fmaf(fv[ii], cr[l + 64 * ii], dt);
#pragma unroll
            for (int off = 1; off < 64; off <<= 1) dt += __shfl_xor(dt, off, 64);
            dbest = 2.f - 2.f * dt;
        }
        for (int ci = 0; ci < cnt; ++ci) {
            int k = s_cand[r][ci];
            if (k == kbest) continue;
            float dt = 0.f;
            const float* cr = codeN + (size_t)k * C_;
#pragma unroll
            for (int ii = 0; ii < 6; ++ii) dt = fmaf(fv[ii], cr[l + 64 * ii], dt);
#pragma unroll
            for (int off = 1; off < 64; off <<= 1) dt += __shfl_xor(dt, off, 64);
            float dex = 2.f - 2.f * dt;
            if (dex < dbest || (dex == dbest && k < kbest)) { dbest = dex; kbest = k; }
        }
        if (l == 0) s_amin[r] = kbest;
    }
    __syncthreads();

    // ---- q gather (CHW), coalesced over px ----
    if (px < MT) {
        const float* cr = codeN + (size_t)s_amin[px] * C_ + kg * 192;
        size_t qb = ((size_t)b * C_ + kg * 192) * HW_ + hw0 + px;
#pragma unroll 1
        for (int c4 = 0; c4 < 48; ++c4) {
            float4 v = *(const float4*)(cr + 4 * c4);
            qOut[qb + (size_t)(4 * c4 + 0) * HW_] = v.x;
            qOut[qb + (size_t)(4 * c4 + 1) * HW_] = v.y;
            qOut[qb + (size_t)(4 * c4 + 2) * HW_] = v.z;
            qOut[qb + (size_t)(4 * c4 + 3) * HW_] = v.w;
        }
    }
}

extern "C" void kernel_launch(void* const* d_in, const int* in_sizes, int n_in,
                              void* d_out, int out_size, void* d_ws, size_t ws_size,
                              hipStream_t stream) {
    const float* feat = (const float*)d_in[0];
    const float* cb   = (const float*)d_in[1];
    float* out    = (float*)d_out;
    float* f_out  = out + OFF_F;
    float* q_out  = out + OFF_Q;
    float* asg    = out + OFF_ASG;
    float* dist   = out + OFF_DIST;

    float* code_n = (float*)d_ws;                            // 3,145,728 B
    u16*   b_hi   = (u16*)((char*)d_ws + 3145728);           // 1,572,864 B
    float* inv_n  = (float*)((char*)d_ws + 4718592);         //   100,352 B

    k_code<<<K_ / 4, 256, 0, stream>>>(cb, code_n, b_hi);
    k_prep<<<dim3(HW_ / 16, B_), 256, 0, stream>>>(feat, f_out, inv_n, (u16*)dist);
    k_fused<<<N_ / MT, 256, 0, stream>>>(b_hi, code_n, inv_n, feat, dist, asg, q_out);
}

// Round 4
// 344.532 us; speedup vs baseline: 1.4271x; 1.4271x over previous
//
#include <hip/hip_runtime.h>

#define B_  32
#define C_  384
#define HW_ 784
#define N_  25088   // B_*HW_
#define K_  2048
#define PPX 112     // pixels per post/q block; 7*112=784

#define OFF_F    0
#define OFF_Q    9633792
#define OFF_ASG  19267584
#define OFF_DIST 70647808

#define MARGIN 0.02f

typedef unsigned short u16;
typedef unsigned int u32;
typedef unsigned long long u64;
typedef __attribute__((ext_vector_type(8))) short short8;
typedef __attribute__((ext_vector_type(4))) float floatx4;

static __device__ __forceinline__ u16 f2bf(float x) {
    u32 u = __builtin_bit_cast(u32, x);
    u32 r = (u + 0x7FFFu + ((u >> 16) & 1u)) >> 16;
    return (u16)r;
}

static __device__ __forceinline__ void gload_lds16(const void* g, void* l) {
    __builtin_amdgcn_global_load_lds(
        (const __attribute__((address_space(1))) unsigned int*)g,
        (__attribute__((address_space(3))) unsigned int*)l,
        16, 0, 0);
}

// per-pixel scratch slots inside the q output region: slot s of pixel (b,hw)
// s=0..15 esum partial per kpanel, 16..31 min key, 32..47 min col,
// 48 candidate count, 49..64 candidate k's. All overwritten by k_q's final gather.
static __device__ __forceinline__ size_t qslot(int b, int s, int hw) {
    return ((size_t)b * C_ + s) * HW_ + hw;
}
static __device__ __forceinline__ u32 dkey(float d) {
    u32 bits = __builtin_bit_cast(u32, d);
    return bits ^ (u32)(((int)bits >> 31) | (int)0x80000000);
}
static __device__ __forceinline__ float key2f(u32 key) {
    u32 bits = (key & 0x80000000u) ? (key ^ 0x80000000u) : ~key;
    return __builtin_bit_cast(float, bits);
}

// ---------------- K1: normalize codebook -> code_n (ws) + b_hi (asg region) ----------------
__global__ __launch_bounds__(256) void k_code(const float* __restrict__ cb,
                                              float* __restrict__ code_n,
                                              u16* __restrict__ b_hi) {
    int row  = blockIdx.x * 4 + (threadIdx.x >> 6);
    int lane = threadIdx.x & 63;
    const float* src = cb + (size_t)row * C_;
    float v[6];
    float ss = 0.f;
#pragma unroll
    for (int i = 0; i < 6; ++i) { v[i] = src[lane + 64 * i]; ss += v[i] * v[i]; }
#pragma unroll
    for (int off = 32; off; off >>= 1) ss += __shfl_xor(ss, off, 64);
    float inv = 1.f / fmaxf(sqrtf(ss), 1e-12f);
#pragma unroll
    for (int i = 0; i < 6; ++i) {
        float vn = v[i] * inv;
        code_n[(size_t)row * C_ + lane + 64 * i] = vn;
        b_hi  [(size_t)row * C_ + lane + 64 * i] = f2bf(vn);
    }
}

// ---------------- K2: feat -> f, inv_n (ws), a_hi (asg region), zero cand-count ----------------
__global__ __launch_bounds__(256) void k_prep(const float* __restrict__ feat,
                                              float* __restrict__ f_out,
                                              float* __restrict__ inv_n,
                                              u16* __restrict__ a_hi,
                                              u32* __restrict__ Qi) {
    __shared__ float tile[C_][17];
    __shared__ float red[16][17];
    __shared__ float s_inv[16];
    int b   = blockIdx.y;
    int hw0 = blockIdx.x * 16;
    int tid = threadIdx.x;
    int px  = tid & 15, cq = tid >> 4;

#pragma unroll
    for (int it = 0; it < 24; ++it) {
        int c = cq + 16 * it;
        tile[c][px] = feat[((size_t)(b * C_ + c)) * HW_ + hw0 + px];
    }
    __syncthreads();
    float ss = 0.f;
#pragma unroll
    for (int q = 0; q < 24; ++q) {
        float v = tile[cq + 16 * q][px];
        ss = fmaf(v, v, ss);
    }
    red[cq][px] = ss;
    __syncthreads();
    if (tid < 16) {
        float tot = 0.f;
#pragma unroll
        for (int p = 0; p < 16; ++p) tot += red[p][tid];
        float inv = 1.f / fmaxf(sqrtf(tot), 1e-12f);
        s_inv[tid] = inv;
        inv_n[(size_t)b * HW_ + hw0 + tid] = inv;
        Qi[qslot(b, 48, hw0 + tid)] = 0;           // zero candidate count
    }
    __syncthreads();

    // f (N,C layout)
    {
        int p2 = tid >> 4, cc = tid & 15;
        size_t nbase = ((size_t)(b * HW_ + hw0 + p2)) * C_;
#pragma unroll
        for (int it = 0; it < 24; ++it) {
            int c = cc + 16 * it;
            f_out[nbase + c] = tile[c][p2];
        }
    }
    // a_hi (normalized bf16, N,C contiguous, packed u32 writes)
    {
        int p2 = tid >> 4, cc = tid & 15;
        float inv = s_inv[p2];
        u16* aptr = a_hi + ((size_t)(b * HW_ + hw0 + p2)) * C_;
#pragma unroll
        for (int it = 0; it < 12; ++it) {
            int c0 = 2 * cc + 32 * it;
            u16 h0 = f2bf(tile[c0][p2] * inv);
            u16 h1 = f2bf(tile[c0 + 1][p2] * inv);
            *(u32*)(aptr + c0) = (u32)h0 | ((u32)h1 << 16);
        }
    }
}

// ---------------- K3: bf16 MFMA GEMM + per-row partial stats ----------------
__global__ __launch_bounds__(256) void k_gemm(const u16* __restrict__ A,
                                              const u16* __restrict__ Bm,
                                              float* __restrict__ D,
                                              u32* __restrict__ Qi) {
    __shared__ u16 As[2][128 * 32];
    __shared__ u16 Bs[2][128 * 32];
    __shared__ float s_es[4][64];
    __shared__ u64   s_mn[4][64];
    int tid = threadIdx.x;
    int kp = blockIdx.x;
    int n0 = kp * 128, m0 = blockIdx.y * 128;
    int w = tid >> 6, l = tid & 63;
    int wm = (w >> 1) * 64, wn = (w & 1) * 64;
    int q4 = l >> 4, r15 = l & 15;

    floatx4 acc[4][4];
#pragma unroll
    for (int i = 0; i < 4; ++i)
#pragma unroll
        for (int j = 0; j < 4; ++j) acc[i][j] = (floatx4)0.f;

    int srow = tid >> 2;
    int sp   = tid & 3;
    int fs   = (srow ^ (srow >> 2)) & 3;
    int kk0  = 8 * (sp ^ fs);

#define STAGE(buf, kt)                                                          \
    {                                                                           \
        _Pragma("unroll")                                                       \
        for (int q = 0; q < 2; ++q) {                                           \
            int row = q * 64 + srow;                                            \
            int off = (q * 256 + tid) * 16;                                     \
            gload_lds16(A  + (size_t)(m0 + row) * C_ + (kt) + kk0,              \
                        (char*)As[buf] + off);                                  \
            gload_lds16(Bm + (size_t)(n0 + row) * C_ + (kt) + kk0,              \
                        (char*)Bs[buf] + off);                                  \
        }                                                                       \
    }

    STAGE(0, 0);
    __syncthreads();

    const int slot = (q4 ^ ((r15 ^ (r15 >> 2)) & 3)) << 4;
#pragma unroll 1
    for (int t = 0; t < 12; ++t) {
        int cur = t & 1;
        if (t < 11) STAGE(cur ^ 1, (t + 1) * 32);
        const char* Ab = (const char*)As[cur];
        const char* Bb = (const char*)Bs[cur];
        short8 a[4], b[4];
#pragma unroll
        for (int i = 0; i < 4; ++i) {
            a[i] = *(const short8*)(Ab + (wm + i * 16 + r15) * 64 + slot);
            b[i] = *(const short8*)(Bb + (wn + i * 16 + r15) * 64 + slot);
        }
#pragma unroll
        for (int i = 0; i < 4; ++i)
#pragma unroll
            for (int j = 0; j < 4; ++j)
                acc[i][j] = __builtin_amdgcn_mfma_f32_16x16x32_bf16(a[i], b[j], acc[i][j], 0, 0, 0);
        __syncthreads();
    }

    // epilogue: write dist + per-row (esum, packed min) partials
#pragma unroll
    for (int i = 0; i < 4; ++i) {
#pragma unroll
        for (int rr = 0; rr < 4; ++rr) {
            int row_l = wm + i * 16 + q4 * 4 + rr;
            int grow  = m0 + row_l;
            float esum = 0.f;
            u64 mk = ~0ull;
#pragma unroll
            for (int j = 0; j < 4; ++j) {
                float d = 2.f - 2.f * acc[i][j][rr];
                int col = n0 + wn + j * 16 + r15;
                D[(size_t)grow * K_ + col] = d;
                esum += __expf(-10.f * d);
                u64 pk = ((u64)dkey(d) << 32) | (u32)col;
                if (pk < mk) mk = pk;
            }
#pragma unroll
            for (int off = 1; off < 16; off <<= 1) {
                esum += __shfl_xor(esum, off, 16);
                u64 om = __shfl_xor(mk, off, 16);
                if (om < mk) mk = om;
            }
            if (r15 == 0) {
                s_es[w][row_l & 63] = esum;
                s_mn[w][row_l & 63] = mk;
            }
        }
    }
    __syncthreads();
    if (tid < 128) {
        int half = tid >> 6, idx = tid & 63;
        float es = s_es[half * 2][idx] + s_es[half * 2 + 1][idx];
        u64 mk = s_mn[half * 2][idx];
        u64 m2 = s_mn[half * 2 + 1][idx];
        if (m2 < mk) mk = m2;
        int n = m0 + tid;
        int b = n / HW_;
        int hw = n - b * HW_;
        Qi[qslot(b, kp,      hw)] = __builtin_bit_cast(u32, es);
        Qi[qslot(b, 16 + kp, hw)] = (u32)(mk >> 32);
        Qi[qslot(b, 32 + kp, hw)] = (u32)(mk & 0xffffffffu);
    }
#undef STAGE
}

// ---------------- K4: single-pass assignment + candidate collection ----------------
// grid (224 hw-tiles, 4 k-chunks of 512)
__global__ __launch_bounds__(256) void k_post(const float* __restrict__ D,
                                              u32* __restrict__ Qi,
                                              float* __restrict__ asg) {
    __shared__ float s_part[48][PPX];
    __shared__ float tbuf[64][113];
    __shared__ float s_inv[PPX], s_thr[PPX];
    int tile = blockIdx.x;
    int kc   = blockIdx.y;
    int b    = tile / 7;
    int hw0  = (tile - b * 7) * PPX;
    int n0   = b * HW_ + hw0;
    int tid  = threadIdx.x;
    const float* Qf = (const float*)Qi;

    // load partial slots 0..47 for 112 pixels (coalesced per slot)
#pragma unroll
    for (int s0 = 0; s0 < 48; s0 += 2) {
        int s = s0 + (tid >> 7);
        int p = tid & 127;
        if (p < PPX) s_part[s][p] = Qf[qslot(b, s, hw0 + p)];
    }
    __syncthreads();
    if (tid < PPX) {
        float es = 0.f;
#pragma unroll
        for (int kp = 0; kp < 16; ++kp) es += s_part[kp][tid];
        u64 mk = ~0ull;
#pragma unroll
        for (int kp = 0; kp < 16; ++kp) {
            u32 key = __builtin_bit_cast(u32, s_part[16 + kp][tid]);
            u32 col = __builtin_bit_cast(u32, s_part[32 + kp][tid]);
            u64 pk = ((u64)key << 32) | col;
            if (pk < mk) mk = pk;
        }
        s_inv[tid] = 1.f / es;
        s_thr[tid] = key2f((u32)(mk >> 32)) + MARGIN;
    }
    __syncthreads();

    int r16 = tid >> 4, c4 = (tid & 15) * 4;
    int px = tid & 127, kg = tid >> 7;
#pragma unroll 1
    for (int ch = 0; ch < 8; ++ch) {
        int k0 = kc * 512 + ch * 64;
#pragma unroll
        for (int rr = 0; rr < 7; ++rr) {
            int row = r16 + 16 * rr;
            float4 dv = *(const float4*)(D + (size_t)(n0 + row) * K_ + k0 + c4);
            float inv = s_inv[row], thr = s_thr[row];
            float dd[4] = {dv.x, dv.y, dv.z, dv.w};
#pragma unroll
            for (int cc = 0; cc < 4; ++cc) {
                float d = dd[cc];
                tbuf[c4 + cc][row] = __expf(-10.f * d) * inv;
                if (d <= thr) {
                    u32 idx = atomicAdd(&Qi[qslot(b, 48, hw0 + row)], 1u);
                    if (idx < 16) Qi[qslot(b, 49 + idx, hw0 + row)] = (u32)(k0 + c4 + cc);
                }
            }
        }
        __syncthreads();
        if (px < PPX) {
            size_t base = ((size_t)(b * K_ + k0 + kg * 32)) * HW_ + hw0 + px;
#pragma unroll
            for (int ki = 0; ki < 32; ++ki)
                asg[base + (size_t)ki * HW_] = tbuf[kg * 32 + ki][px];
        }
        __syncthreads();
    }
}

// ---------------- K5: argmin (+exact recheck) and q gather ----------------
__global__ __launch_bounds__(256) void k_q(const u32* __restrict__ Qi,
                                           const float* __restrict__ codeN,
                                           const float* __restrict__ invN,
                                           const float* __restrict__ feat,
                                           float* __restrict__ qOut) {
    __shared__ int s_amin[PPX], s_cnt[PPX], s_cand[PPX][16];
    int tile = blockIdx.x;
    int b    = tile / 7;
    int hw0  = (tile - b * 7) * PPX;
    int npix = b * HW_ + hw0;
    int tid  = threadIdx.x;

    if (tid < PPX) {
        u64 mk = ~0ull;
#pragma unroll
        for (int kp = 0; kp < 16; ++kp) {
            u32 key = Qi[qslot(b, 16 + kp, hw0 + tid)];
            u32 col = Qi[qslot(b, 32 + kp, hw0 + tid)];
            u64 pk = ((u64)key << 32) | col;
            if (pk < mk) mk = pk;
        }
        s_amin[tid] = (int)(mk & 0xffffffffu);
        int cnt = (int)Qi[qslot(b, 48, hw0 + tid)];
        cnt = cnt > 16 ? 16 : cnt;
        s_cnt[tid] = cnt;
        for (int ci = 0; ci < cnt; ++ci)
            s_cand[tid][ci] = (int)Qi[qslot(b, 49 + ci, hw0 + tid)];
    }
    __syncthreads();

    // exact fp32 recheck, one wave per ambiguous row
    int w = tid >> 6, l = tid & 63;
#pragma unroll 1
    for (int r = w; r < PPX; r += 4) {
        int cnt = s_cnt[r];
        if (cnt < 2) continue;
        float ivn = invN[npix + r];
        float fv[6];
#pragma unroll
        for (int ii = 0; ii < 6; ++ii)
            fv[ii] = feat[((size_t)b * C_ + l + 64 * ii) * HW_ + hw0 + r] * ivn;
        int kbest = s_amin[r];
        float dbest;
        {
            float dt = 0.f;
            const float* cr = codeN + (size_t)kbest * C_;
#pragma unroll
            for (int ii = 0; ii < 6; ++ii) dt = fmaf(fv[ii], cr[l + 64 * ii], dt);
#pragma unroll
            for (int off = 1; off < 64; off <<= 1) dt += __shfl_xor(dt, off, 64);
            dbest = 2.f - 2.f * dt;
        }
        for (int ci = 0; ci < cnt; ++ci) {
            int k = s_cand[r][ci];
            if (k == kbest) continue;
            float dt = 0.f;
            const float* cr = codeN + (size_t)k * C_;
#pragma unroll
            for (int ii = 0; ii < 6; ++ii) dt = fmaf(fv[ii], cr[l + 64 * ii], dt);
#pragma unroll
            for (int off = 1; off < 64; off <<= 1) dt += __shfl_xor(dt, off, 64);
            float dex = 2.f - 2.f * dt;
            if (dex < dbest || (dex == dbest && k < kbest)) { dbest = dex; kbest = k; }
        }
        if (l == 0) s_amin[r] = kbest;
    }
    __syncthreads();

    // q gather (CHW), 448B coalesced segments; overwrites the scratch slots
    int px = tid & 127, kg = tid >> 7;
    if (px < PPX) {
        const float* cr = codeN + (size_t)s_amin[px] * C_ + kg * 192;
        size_t qb = ((size_t)b * C_ + kg * 192) * HW_ + hw0 + px;
#pragma unroll 1
        for (int c4 = 0; c4 < 48; ++c4) {
            float4 v = *(const float4*)(cr + 4 * c4);
            qOut[qb + (size_t)(4 * c4 + 0) * HW_] = v.x;
            qOut[qb + (size_t)(4 * c4 + 1) * HW_] = v.y;
            qOut[qb + (size_t)(4 * c4 + 2) * HW_] = v.z;
            qOut[qb + (size_t)(4 * c4 + 3) * HW_] = v.w;
        }
    }
}

extern "C" void kernel_launch(void* const* d_in, const int* in_sizes, int n_in,
                              void* d_out, int out_size, void* d_ws, size_t ws_size,
                              hipStream_t stream) {
    const float* feat = (const float*)d_in[0];
    const float* cb   = (const float*)d_in[1];
    float* out    = (float*)d_out;
    float* f_out  = out + OFF_F;
    float* q_out  = out + OFF_Q;     // doubles as per-pixel scratch slots until k_q
    float* asg    = out + OFF_ASG;   // first 20.8 MB holds a_hi/b_hi until k_post
    float* dist   = out + OFF_DIST;

    float* code_n = (float*)d_ws;                       // 3,145,728 B
    float* inv_n  = (float*)((char*)d_ws + 3145728);    //   100,352 B

    u16* a_hi = (u16*)asg;
    u16* b_hi = a_hi + (size_t)N_ * C_;
    u32* Qi   = (u32*)q_out;

    k_code<<<K_ / 4, 256, 0, stream>>>(cb, code_n, b_hi);
    k_prep<<<dim3(HW_ / 16, B_), 256, 0, stream>>>(feat, f_out, inv_n, a_hi, Qi);
    k_gemm<<<dim3(K_ / 128, N_ / 128), 256, 0, stream>>>(a_hi, b_hi, dist, Qi);
    k_post<<<dim3(224, 4), 256, 0, stream>>>(dist, Qi, asg);
    k_q<<<224, 256, 0, stream>>>(Qi, code_n, inv_n, feat, q_out);
}

// Round 5
// 337.419 us; speedup vs baseline: 1.4572x; 1.0211x over previous
//
#include <hip/hip_runtime.h>

#define B_  32
#define C_  384
#define HW_ 784
#define N_  25088   // B_*HW_
#define K_  2048
#define PPX 112     // pixels per post/q block; 7*112=784

#define OFF_F    0
#define OFF_Q    9633792
#define OFF_ASG  19267584
#define OFF_DIST 70647808

#define MARGIN 0.02f

typedef unsigned short u16;
typedef unsigned int u32;
typedef __attribute__((ext_vector_type(8))) short short8;
typedef __attribute__((ext_vector_type(4))) float floatx4;

static __device__ __forceinline__ u16 f2bf(float x) {
    u32 u = __builtin_bit_cast(u32, x);
    u32 r = (u + 0x7FFFu + ((u >> 16) & 1u)) >> 16;
    return (u16)r;
}

static __device__ __forceinline__ void gload_lds16(const void* g, void* l) {
    __builtin_amdgcn_global_load_lds(
        (const __attribute__((address_space(1))) unsigned int*)g,
        (__attribute__((address_space(3))) unsigned int*)l,
        16, 0, 0);
}

// per-pixel scratch slots inside the q output region (overwritten by k_q gather):
// s=0..15 esum partial per k-panel, 16..31 dmin partial, 48 cand count, 49..64 cand k
static __device__ __forceinline__ size_t qslot(int b, int s, int hw) {
    return ((size_t)b * C_ + s) * HW_ + hw;
}

// ---------------- K1: normalize codebook -> code_n (ws) + b_hi (asg region) ----------------
__global__ __launch_bounds__(256) void k_code(const float* __restrict__ cb,
                                              float* __restrict__ code_n,
                                              u16* __restrict__ b_hi) {
    int row  = blockIdx.x * 4 + (threadIdx.x >> 6);
    int lane = threadIdx.x & 63;
    const float* src = cb + (size_t)row * C_;
    float v[6];
    float ss = 0.f;
#pragma unroll
    for (int i = 0; i < 6; ++i) { v[i] = src[lane + 64 * i]; ss += v[i] * v[i]; }
#pragma unroll
    for (int off = 32; off; off >>= 1) ss += __shfl_xor(ss, off, 64);
    float inv = 1.f / fmaxf(sqrtf(ss), 1e-12f);
#pragma unroll
    for (int i = 0; i < 6; ++i) {
        float vn = v[i] * inv;
        code_n[(size_t)row * C_ + lane + 64 * i] = vn;
        b_hi  [(size_t)row * C_ + lane + 64 * i] = f2bf(vn);
    }
}

// ---------------- K2: feat -> f, inv_n (ws), a_hi (asg region), zero cand-count ----------------
__global__ __launch_bounds__(256) void k_prep(const float* __restrict__ feat,
                                              float* __restrict__ f_out,
                                              float* __restrict__ inv_n,
                                              u16* __restrict__ a_hi,
                                              u32* __restrict__ Qi) {
    __shared__ float tile[C_][17];
    __shared__ float red[16][17];
    __shared__ float s_inv[16];
    int b   = blockIdx.y;
    int hw0 = blockIdx.x * 16;
    int tid = threadIdx.x;
    int px  = tid & 15, cq = tid >> 4;

#pragma unroll
    for (int it = 0; it < 24; ++it) {
        int c = cq + 16 * it;
        tile[c][px] = feat[((size_t)(b * C_ + c)) * HW_ + hw0 + px];
    }
    __syncthreads();
    float ss = 0.f;
#pragma unroll
    for (int q = 0; q < 24; ++q) {
        float v = tile[cq + 16 * q][px];
        ss = fmaf(v, v, ss);
    }
    red[cq][px] = ss;
    __syncthreads();
    if (tid < 16) {
        float tot = 0.f;
#pragma unroll
        for (int p = 0; p < 16; ++p) tot += red[p][tid];
        float inv = 1.f / fmaxf(sqrtf(tot), 1e-12f);
        s_inv[tid] = inv;
        inv_n[(size_t)b * HW_ + hw0 + tid] = inv;
        Qi[qslot(b, 48, hw0 + tid)] = 0;           // zero candidate count
    }
    __syncthreads();

    // f (N,C layout), float4 stores
    {
        int p2 = tid >> 4, cc = tid & 15;
        float* fb = f_out + ((size_t)(b * HW_ + hw0 + p2)) * C_;
#pragma unroll
        for (int it = 0; it < 6; ++it) {
            int c0 = cc * 4 + 64 * it;
            float4 v;
            v.x = tile[c0 + 0][p2];
            v.y = tile[c0 + 1][p2];
            v.z = tile[c0 + 2][p2];
            v.w = tile[c0 + 3][p2];
            *(float4*)(fb + c0) = v;
        }
    }
    // a_hi (normalized bf16, N,C contiguous, packed u32 writes)
    {
        int p2 = tid >> 4, cc = tid & 15;
        float inv = s_inv[p2];
        u16* aptr = a_hi + ((size_t)(b * HW_ + hw0 + p2)) * C_;
#pragma unroll
        for (int it = 0; it < 12; ++it) {
            int c0 = 2 * cc + 32 * it;
            u16 h0 = f2bf(tile[c0][p2] * inv);
            u16 h1 = f2bf(tile[c0 + 1][p2] * inv);
            *(u32*)(aptr + c0) = (u32)h0 | ((u32)h1 << 16);
        }
    }
}

// ---------------- K3: bf16 MFMA GEMM + cheap per-row partial stats ----------------
__global__ __launch_bounds__(256) void k_gemm(const u16* __restrict__ A,
                                              const u16* __restrict__ Bm,
                                              float* __restrict__ D,
                                              u32* __restrict__ Qi) {
    __shared__ u16 As[2][128 * 32];
    __shared__ u16 Bs[2][128 * 32];
    __shared__ float s_es[4][64];
    __shared__ float s_dm[4][64];
    int tid = threadIdx.x;
    int kp = blockIdx.x;
    int n0 = kp * 128, m0 = blockIdx.y * 128;
    int w = tid >> 6, l = tid & 63;
    int wm = (w >> 1) * 64, wn = (w & 1) * 64;
    int q4 = l >> 4, r15 = l & 15;

    floatx4 acc[4][4];
#pragma unroll
    for (int i = 0; i < 4; ++i)
#pragma unroll
        for (int j = 0; j < 4; ++j) acc[i][j] = (floatx4)0.f;

    int srow = tid >> 2;
    int sp   = tid & 3;
    int fs   = (srow ^ (srow >> 2)) & 3;
    int kk0  = 8 * (sp ^ fs);

#define STAGE(buf, kt)                                                          \
    {                                                                           \
        _Pragma("unroll")                                                       \
        for (int q = 0; q < 2; ++q) {                                           \
            int row = q * 64 + srow;                                            \
            int off = (q * 256 + tid) * 16;                                     \
            gload_lds16(A  + (size_t)(m0 + row) * C_ + (kt) + kk0,              \
                        (char*)As[buf] + off);                                  \
            gload_lds16(Bm + (size_t)(n0 + row) * C_ + (kt) + kk0,              \
                        (char*)Bs[buf] + off);                                  \
        }                                                                       \
    }

    STAGE(0, 0);
    __syncthreads();

    const int slot = (q4 ^ ((r15 ^ (r15 >> 2)) & 3)) << 4;
#pragma unroll 1
    for (int t = 0; t < 12; ++t) {
        int cur = t & 1;
        if (t < 11) STAGE(cur ^ 1, (t + 1) * 32);
        const char* Ab = (const char*)As[cur];
        const char* Bb = (const char*)Bs[cur];
        short8 a[4], b[4];
#pragma unroll
        for (int i = 0; i < 4; ++i) {
            a[i] = *(const short8*)(Ab + (wm + i * 16 + r15) * 64 + slot);
            b[i] = *(const short8*)(Bb + (wn + i * 16 + r15) * 64 + slot);
        }
#pragma unroll
        for (int i = 0; i < 4; ++i)
#pragma unroll
            for (int j = 0; j < 4; ++j)
                acc[i][j] = __builtin_amdgcn_mfma_f32_16x16x32_bf16(a[i], b[j], acc[i][j], 0, 0, 0);
        __syncthreads();
    }

    // epilogue: write dist + per-row (esum, dmin) float partials
#pragma unroll
    for (int i = 0; i < 4; ++i) {
#pragma unroll
        for (int rr = 0; rr < 4; ++rr) {
            int row_l = wm + i * 16 + q4 * 4 + rr;
            int grow  = m0 + row_l;
            float esum = 0.f, dmin = 3.4e38f;
#pragma unroll
            for (int j = 0; j < 4; ++j) {
                float d = 2.f - 2.f * acc[i][j][rr];
                D[(size_t)grow * K_ + n0 + wn + j * 16 + r15] = d;
                esum += __expf(-10.f * d);
                dmin = fminf(dmin, d);
            }
#pragma unroll
            for (int off = 1; off < 16; off <<= 1) {
                esum += __shfl_xor(esum, off, 16);
                dmin = fminf(dmin, __shfl_xor(dmin, off, 16));
            }
            if (r15 == 0) {
                s_es[w][row_l & 63] = esum;
                s_dm[w][row_l & 63] = dmin;
            }
        }
    }
    __syncthreads();
    if (tid < 128) {
        int half = tid >> 6, idx = tid & 63;
        float es = s_es[half * 2][idx] + s_es[half * 2 + 1][idx];
        float dm = fminf(s_dm[half * 2][idx], s_dm[half * 2 + 1][idx]);
        int n = m0 + tid;
        int b = n / HW_;
        int hw = n - b * HW_;
        Qi[qslot(b, kp,      hw)] = __builtin_bit_cast(u32, es);
        Qi[qslot(b, 16 + kp, hw)] = __builtin_bit_cast(u32, dm);
    }
#undef STAGE
}

// ---------------- K4: single-pass assignment + candidate collection ----------------
// grid (224 hw-tiles, 4 k-chunks of 512)
__global__ __launch_bounds__(256) void k_post(const float* __restrict__ D,
                                              u32* __restrict__ Qi,
                                              float* __restrict__ asg) {
    __shared__ float s_part[32][PPX];
    __shared__ float tbuf[64][113];
    __shared__ float s_inv[PPX], s_thr[PPX];
    int tile = blockIdx.x;
    int kc   = blockIdx.y;
    int b    = tile / 7;
    int hw0  = (tile - b * 7) * PPX;
    int n0   = b * HW_ + hw0;
    int tid  = threadIdx.x;
    const float* Qf = (const float*)Qi;

#pragma unroll
    for (int s0 = 0; s0 < 32; s0 += 2) {
        int s = s0 + (tid >> 7);
        int p = tid & 127;
        if (p < PPX) s_part[s][p] = Qf[qslot(b, s, hw0 + p)];
    }
    __syncthreads();
    if (tid < PPX) {
        float es = 0.f;
#pragma unroll
        for (int kp = 0; kp < 16; ++kp) es += s_part[kp][tid];
        float dm = 3.4e38f;
#pragma unroll
        for (int kp = 0; kp < 16; ++kp) dm = fminf(dm, s_part[16 + kp][tid]);
        s_inv[tid] = 1.f / es;
        s_thr[tid] = dm + MARGIN;
    }
    __syncthreads();

    int r16 = tid >> 4, c4 = (tid & 15) * 4;
    int px = tid & 127, kg = tid >> 7;
#pragma unroll 1
    for (int ch = 0; ch < 8; ++ch) {
        int k0 = kc * 512 + ch * 64;
#pragma unroll
        for (int rr = 0; rr < 7; ++rr) {
            int row = r16 + 16 * rr;
            float4 dv = *(const float4*)(D + (size_t)(n0 + row) * K_ + k0 + c4);
            float inv = s_inv[row], thr = s_thr[row];
            float dd[4] = {dv.x, dv.y, dv.z, dv.w};
#pragma unroll
            for (int cc = 0; cc < 4; ++cc) {
                float d = dd[cc];
                tbuf[c4 + cc][row] = __expf(-10.f * d) * inv;
                if (d <= thr) {
                    u32 idx = atomicAdd(&Qi[qslot(b, 48, hw0 + row)], 1u);
                    if (idx < 16) Qi[qslot(b, 49 + idx, hw0 + row)] = (u32)(k0 + c4 + cc);
                }
            }
        }
        __syncthreads();
        if (px < PPX) {
            size_t base = ((size_t)(b * K_ + k0 + kg * 32)) * HW_ + hw0 + px;
#pragma unroll
            for (int ki = 0; ki < 32; ++ki)
                asg[base + (size_t)ki * HW_] = tbuf[kg * 32 + ki][px];
        }
        __syncthreads();
    }
}

// ---------------- K5: argmin via exact recheck of candidates, q gather ----------------
__global__ __launch_bounds__(256) void k_q(const u32* __restrict__ Qi,
                                           const float* __restrict__ codeN,
                                           const float* __restrict__ invN,
                                           const float* __restrict__ f_in,
                                           float* __restrict__ qOut) {
    __shared__ int s_amin[PPX], s_cnt[PPX], s_cand[PPX][16];
    int tile = blockIdx.x;
    int b    = tile / 7;
    int hw0  = (tile - b * 7) * PPX;
    int npix = b * HW_ + hw0;
    int tid  = threadIdx.x;

    if (tid < PPX) {
        int cnt = (int)Qi[qslot(b, 48, hw0 + tid)];
        cnt = cnt > 16 ? 16 : cnt;
        s_cnt[tid] = cnt;
        int k0 = 0;
        for (int ci = 0; ci < cnt; ++ci) {
            int kv = (int)Qi[qslot(b, 49 + ci, hw0 + tid)];
            s_cand[tid][ci] = kv;
            if (ci == 0) k0 = kv;
        }
        s_amin[tid] = k0;
    }
    __syncthreads();

    // exact fp32 recheck, one wave per ambiguous row (reads f_out contiguous)
    int w = tid >> 6, l = tid & 63;
#pragma unroll 1
    for (int r = w; r < PPX; r += 4) {
        int cnt = s_cnt[r];
        if (cnt < 2) continue;
        float ivn = invN[npix + r];
        float fv[6];
        const float* frow = f_in + (size_t)(npix + r) * C_;
#pragma unroll
        for (int ii = 0; ii < 6; ++ii)
            fv[ii] = frow[l + 64 * ii] * ivn;
        float dbest = 3.4e38f;
        int   kbest = -1;
        for (int ci = 0; ci < cnt; ++ci) {
            int k = s_cand[r][ci];
            float dt = 0.f;
            const float* cr = codeN + (size_t)k * C_;
#pragma unroll
            for (int ii = 0; ii < 6; ++ii) dt = fmaf(fv[ii], cr[l + 64 * ii], dt);
#pragma unroll
            for (int off = 1; off < 64; off <<= 1) dt += __shfl_xor(dt, off, 64);
            float dex = 2.f - 2.f * dt;
            if (kbest < 0 || dex < dbest || (dex == dbest && k < kbest)) { dbest = dex; kbest = k; }
        }
        if (l == 0) s_amin[r] = kbest;
    }
    __syncthreads();

    // q gather (CHW), 448B coalesced segments; overwrites the scratch slots
    int px = tid & 127, kg = tid >> 7;
    if (px < PPX) {
        const float* cr = codeN + (size_t)s_amin[px] * C_ + kg * 192;
        size_t qb = ((size_t)b * C_ + kg * 192) * HW_ + hw0 + px;
#pragma unroll 1
        for (int c4 = 0; c4 < 48; ++c4) {
            float4 v = *(const float4*)(cr + 4 * c4);
            qOut[qb + (size_t)(4 * c4 + 0) * HW_] = v.x;
            qOut[qb + (size_t)(4 * c4 + 1) * HW_] = v.y;
            qOut[qb + (size_t)(4 * c4 + 2) * HW_] = v.z;
            qOut[qb + (size_t)(4 * c4 + 3) * HW_] = v.w;
        }
    }
}

extern "C" void kernel_launch(void* const* d_in, const int* in_sizes, int n_in,
                              void* d_out, int out_size, void* d_ws, size_t ws_size,
                              hipStream_t stream) {
    const float* feat = (const float*)d_in[0];
    const float* cb   = (const float*)d_in[1];
    float* out    = (float*)d_out;
    float* f_out  = out + OFF_F;
    float* q_out  = out + OFF_Q;     // doubles as per-pixel scratch slots until k_q
    float* asg    = out + OFF_ASG;   // first 20.8 MB holds a_hi/b_hi until k_post
    float* dist   = out + OFF_DIST;

    float* code_n = (float*)d_ws;                       // 3,145,728 B
    float* inv_n  = (float*)((char*)d_ws + 3145728);    //   100,352 B

    u16* a_hi = (u16*)asg;
    u16* b_hi = a_hi + (size_t)N_ * C_;
    u32* Qi   = (u32*)q_out;

    k_code<<<K_ / 4, 256, 0, stream>>>(cb, code_n, b_hi);
    k_prep<<<dim3(HW_ / 16, B_), 256, 0, stream>>>(feat, f_out, inv_n, a_hi, Qi);
    k_gemm<<<dim3(K_ / 128, N_ / 128), 256, 0, stream>>>(a_hi, b_hi, dist, Qi);
    k_post<<<dim3(224, 4), 256, 0, stream>>>(dist, Qi, asg);
    k_q<<<224, 256, 0, stream>>>(Qi, code_n, inv_n, f_out, q_out);
}

// Round 6
// 303.264 us; speedup vs baseline: 1.6213x; 1.1126x over previous
//
#include <hip/hip_runtime.h>

#define B_  32
#define C_  384
#define HW_ 784
#define N_  25088   // B_*HW_
#define K_  2048
#define PPX 112     // pixels per post/q block; 7*112=784

#define OFF_F    0
#define OFF_Q    9633792
#define OFF_ASG  19267584
#define OFF_DIST 70647808

#define MARGIN 0.02f

typedef unsigned short u16;
typedef unsigned int u32;
typedef __attribute__((ext_vector_type(8))) short short8;
typedef __attribute__((ext_vector_type(4))) float floatx4;

static __device__ __forceinline__ u16 f2bf(float x) {
    u32 u = __builtin_bit_cast(u32, x);
    u32 r = (u + 0x7FFFu + ((u >> 16) & 1u)) >> 16;
    return (u16)r;
}

static __device__ __forceinline__ void gload_lds16(const void* g, void* l) {
    __builtin_amdgcn_global_load_lds(
        (const __attribute__((address_space(1))) unsigned int*)g,
        (__attribute__((address_space(3))) unsigned int*)l,
        16, 0, 0);
}

// candidate scratch in the q output region (overwritten by k_q's final gather):
// per (b, hw): slot s = chunk*17 -> count, s = chunk*17+1+ci -> candidate k
static __device__ __forceinline__ size_t qslot(int b, int s, int hw) {
    return ((size_t)b * C_ + s) * HW_ + hw;
}

// ---------------- K1: normalize codebook -> code_n (ws) + b_hi (asg region) ----------------
__global__ __launch_bounds__(256) void k_code(const float* __restrict__ cb,
                                              float* __restrict__ code_n,
                                              u16* __restrict__ b_hi) {
    int row  = blockIdx.x * 4 + (threadIdx.x >> 6);
    int lane = threadIdx.x & 63;
    const float* src = cb + (size_t)row * C_;
    float v[6];
    float ss = 0.f;
#pragma unroll
    for (int i = 0; i < 6; ++i) { v[i] = src[lane + 64 * i]; ss += v[i] * v[i]; }
#pragma unroll
    for (int off = 32; off; off >>= 1) ss += __shfl_xor(ss, off, 64);
    float inv = 1.f / fmaxf(sqrtf(ss), 1e-12f);
#pragma unroll
    for (int i = 0; i < 6; ++i) {
        float vn = v[i] * inv;
        code_n[(size_t)row * C_ + lane + 64 * i] = vn;
        b_hi  [(size_t)row * C_ + lane + 64 * i] = f2bf(vn);
    }
}

// ---------------- K2: feat -> f, inv_n (ws), a_hi (asg region) ----------------
__global__ __launch_bounds__(256) void k_prep(const float* __restrict__ feat,
                                              float* __restrict__ f_out,
                                              float* __restrict__ inv_n,
                                              u16* __restrict__ a_hi) {
    __shared__ float tile[C_][17];
    __shared__ float red[16][17];
    __shared__ float s_inv[16];
    int b   = blockIdx.y;
    int hw0 = blockIdx.x * 16;
    int tid = threadIdx.x;
    int px  = tid & 15, cq = tid >> 4;

#pragma unroll
    for (int it = 0; it < 24; ++it) {
        int c = cq + 16 * it;
        tile[c][px] = feat[((size_t)(b * C_ + c)) * HW_ + hw0 + px];
    }
    __syncthreads();
    float ss = 0.f;
#pragma unroll
    for (int q = 0; q < 24; ++q) {
        float v = tile[cq + 16 * q][px];
        ss = fmaf(v, v, ss);
    }
    red[cq][px] = ss;
    __syncthreads();
    if (tid < 16) {
        float tot = 0.f;
#pragma unroll
        for (int p = 0; p < 16; ++p) tot += red[p][tid];
        float inv = 1.f / fmaxf(sqrtf(tot), 1e-12f);
        s_inv[tid] = inv;
        inv_n[(size_t)b * HW_ + hw0 + tid] = inv;
    }
    __syncthreads();

    // f (N,C layout), float4 stores
    {
        int p2 = tid >> 4, cc = tid & 15;
        float* fb = f_out + ((size_t)(b * HW_ + hw0 + p2)) * C_;
#pragma unroll
        for (int it = 0; it < 6; ++it) {
            int c0 = cc * 4 + 64 * it;
            float4 v;
            v.x = tile[c0 + 0][p2];
            v.y = tile[c0 + 1][p2];
            v.z = tile[c0 + 2][p2];
            v.w = tile[c0 + 3][p2];
            *(float4*)(fb + c0) = v;
        }
    }
    // a_hi (normalized bf16, N,C contiguous, packed u32 writes)
    {
        int p2 = tid >> 4, cc = tid & 15;
        float inv = s_inv[p2];
        u16* aptr = a_hi + ((size_t)(b * HW_ + hw0 + p2)) * C_;
#pragma unroll
        for (int it = 0; it < 12; ++it) {
            int c0 = 2 * cc + 32 * it;
            u16 h0 = f2bf(tile[c0][p2] * inv);
            u16 h1 = f2bf(tile[c0 + 1][p2] * inv);
            *(u32*)(aptr + c0) = (u32)h0 | ((u32)h1 << 16);
        }
    }
}

// ---------------- K3: pure bf16 MFMA GEMM, dist = 2 - 2 * A.B^T ----------------
__global__ __launch_bounds__(256) void k_gemm(const u16* __restrict__ A,
                                              const u16* __restrict__ Bm,
                                              float* __restrict__ D) {
    __shared__ u16 As[2][128 * 32];
    __shared__ u16 Bs[2][128 * 32];
    int tid = threadIdx.x;
    int n0 = blockIdx.x * 128, m0 = blockIdx.y * 128;
    int w = tid >> 6, l = tid & 63;
    int wm = (w >> 1) * 64, wn = (w & 1) * 64;
    int q4 = l >> 4, r15 = l & 15;

    floatx4 acc[4][4];
#pragma unroll
    for (int i = 0; i < 4; ++i)
#pragma unroll
        for (int j = 0; j < 4; ++j) acc[i][j] = (floatx4)0.f;

    int srow = tid >> 2;
    int sp   = tid & 3;
    int fs   = (srow ^ (srow >> 2)) & 3;
    int kk0  = 8 * (sp ^ fs);

#define STAGE(buf, kt)                                                          \
    {                                                                           \
        _Pragma("unroll")                                                       \
        for (int q = 0; q < 2; ++q) {                                           \
            int row = q * 64 + srow;                                            \
            int off = (q * 256 + tid) * 16;                                     \
            gload_lds16(A  + (size_t)(m0 + row) * C_ + (kt) + kk0,              \
                        (char*)As[buf] + off);                                  \
            gload_lds16(Bm + (size_t)(n0 + row) * C_ + (kt) + kk0,              \
                        (char*)Bs[buf] + off);                                  \
        }                                                                       \
    }

    STAGE(0, 0);
    __syncthreads();

    const int slot = (q4 ^ ((r15 ^ (r15 >> 2)) & 3)) << 4;
#pragma unroll 1
    for (int t = 0; t < 12; ++t) {
        int cur = t & 1;
        if (t < 11) STAGE(cur ^ 1, (t + 1) * 32);
        const char* Ab = (const char*)As[cur];
        const char* Bb = (const char*)Bs[cur];
        short8 a[4], b[4];
#pragma unroll
        for (int i = 0; i < 4; ++i) {
            a[i] = *(const short8*)(Ab + (wm + i * 16 + r15) * 64 + slot);
            b[i] = *(const short8*)(Bb + (wn + i * 16 + r15) * 64 + slot);
        }
#pragma unroll
        for (int i = 0; i < 4; ++i)
#pragma unroll
            for (int j = 0; j < 4; ++j)
                acc[i][j] = __builtin_amdgcn_mfma_f32_16x16x32_bf16(a[i], b[j], acc[i][j], 0, 0, 0);
        __syncthreads();
    }

#pragma unroll
    for (int i = 0; i < 4; ++i) {
        int gm = m0 + wm + i * 16 + q4 * 4;
#pragma unroll
        for (int j = 0; j < 4; ++j) {
            int gn = n0 + wn + j * 16 + r15;
            float* p = D + (size_t)gm * K_ + gn;
#pragma unroll
            for (int r = 0; r < 4; ++r)
                p[(size_t)r * K_] = 2.f - 2.f * acc[i][j][r];
        }
    }
#undef STAGE
}

// ---------------- K4: streaming row stats: (inv, thr) per row ----------------
// one wave per row; 4 rows per block
__global__ __launch_bounds__(256) void k_stats(const float* __restrict__ D,
                                               float2* __restrict__ srow) {
    int row = blockIdx.x * 4 + (threadIdx.x >> 6);
    int l   = threadIdx.x & 63;
    const float* dr = D + (size_t)row * K_;
    float es = 0.f, dm = 3.4e38f;
#pragma unroll
    for (int i = 0; i < 8; ++i) {
        float4 v = *(const float4*)(dr + l * 4 + 256 * i);
        es += __expf(-10.f * v.x) + __expf(-10.f * v.y)
            + __expf(-10.f * v.z) + __expf(-10.f * v.w);
        dm = fminf(dm, fminf(fminf(v.x, v.y), fminf(v.z, v.w)));
    }
#pragma unroll
    for (int off = 32; off; off >>= 1) {
        es += __shfl_xor(es, off, 64);
        dm = fminf(dm, __shfl_xor(dm, off, 64));
    }
    if (l == 0) {
        float2 st;
        st.x = 1.f / es;
        st.y = dm + MARGIN;
        srow[row] = st;
    }
}

// ---------------- K5: assignment + candidate collection ----------------
// grid (224 hw-tiles, 4 k-chunks of 512)
__global__ __launch_bounds__(256) void k_post(const float* __restrict__ D,
                                              const float2* __restrict__ srow,
                                              u32* __restrict__ Qi,
                                              float* __restrict__ asg) {
    __shared__ float tbuf[64][113];
    __shared__ float s_inv[PPX], s_thr[PPX];
    __shared__ int   s_cnt[PPX];
    __shared__ int   s_cand[PPX][16];
    int tile = blockIdx.x;
    int kc   = blockIdx.y;
    int b    = tile / 7;
    int hw0  = (tile - b * 7) * PPX;
    int n0   = b * HW_ + hw0;
    int tid  = threadIdx.x;

    if (tid < PPX) {
        float2 st = srow[n0 + tid];
        s_inv[tid] = st.x;
        s_thr[tid] = st.y;
        s_cnt[tid] = 0;
    }
    __syncthreads();

    int r16 = tid >> 4, c4 = (tid & 15) * 4;
    int px = tid & 127, kg = tid >> 7;
#pragma unroll 1
    for (int ch = 0; ch < 8; ++ch) {
        int k0 = kc * 512 + ch * 64;
#pragma unroll
        for (int rr = 0; rr < 7; ++rr) {
            int row = r16 + 16 * rr;
            float4 dv = *(const float4*)(D + (size_t)(n0 + row) * K_ + k0 + c4);
            float inv = s_inv[row], thr = s_thr[row];
            float dd[4] = {dv.x, dv.y, dv.z, dv.w};
#pragma unroll
            for (int cc = 0; cc < 4; ++cc) {
                float d = dd[cc];
                tbuf[c4 + cc][row] = __expf(-10.f * d) * inv;
                if (d <= thr) {
                    int idx = atomicAdd(&s_cnt[row], 1);
                    if (idx < 16) s_cand[row][idx] = k0 + c4 + cc;
                }
            }
        }
        __syncthreads();
        if (px < PPX) {
            size_t base = ((size_t)(b * K_ + k0 + kg * 32)) * HW_ + hw0 + px;
#pragma unroll
            for (int ki = 0; ki < 32; ++ki)
                asg[base + (size_t)ki * HW_] = tbuf[kg * 32 + ki][px];
        }
        __syncthreads();
    }

    // dump candidate lists for this k-chunk (plain coalesced stores)
    if (tid < PPX) {
        int cnt = s_cnt[tid];
        cnt = cnt > 16 ? 16 : cnt;
        Qi[qslot(b, kc * 17, hw0 + tid)] = (u32)cnt;
        for (int ci = 0; ci < cnt; ++ci)
            Qi[qslot(b, kc * 17 + 1 + ci, hw0 + tid)] = (u32)s_cand[tid][ci];
    }
}

// ---------------- K6: merge candidates, exact recheck, q gather ----------------
__global__ __launch_bounds__(256) void k_q(const u32* __restrict__ Qi,
                                           const float* __restrict__ codeN,
                                           const float* __restrict__ invN,
                                           const float* __restrict__ f_in,
                                           float* __restrict__ qOut) {
    __shared__ int s_amin[PPX], s_cnt[PPX];
    __shared__ int s_cand[PPX][64];
    int tile = blockIdx.x;
    int b    = tile / 7;
    int hw0  = (tile - b * 7) * PPX;
    int npix = b * HW_ + hw0;
    int tid  = threadIdx.x;

    if (tid < PPX) {
        int total = 0;
#pragma unroll
        for (int kc = 0; kc < 4; ++kc) {
            int cnt = (int)Qi[qslot(b, kc * 17, hw0 + tid)];
            for (int ci = 0; ci < cnt; ++ci)
                s_cand[tid][total++] = (int)Qi[qslot(b, kc * 17 + 1 + ci, hw0 + tid)];
        }
        s_cnt[tid]  = total;
        s_amin[tid] = s_cand[tid][0];
    }
    __syncthreads();

    // exact fp32 recheck, one wave per ambiguous row (reads f contiguous)
    int w = tid >> 6, l = tid & 63;
#pragma unroll 1
    for (int r = w; r < PPX; r += 4) {
        int cnt = s_cnt[r];
        if (cnt < 2) continue;
        float ivn = invN[npix + r];
        float fv[6];
        const float* frow = f_in + (size_t)(npix + r) * C_;
#pragma unroll
        for (int ii = 0; ii < 6; ++ii)
            fv[ii] = frow[l + 64 * ii] * ivn;
        float dbest = 3.4e38f;
        int   kbest = -1;
        for (int ci = 0; ci < cnt; ++ci) {
            int k = s_cand[r][ci];
            float dt = 0.f;
            const float* cr = codeN + (size_t)k * C_;
#pragma unroll
            for (int ii = 0; ii < 6; ++ii) dt = fmaf(fv[ii], cr[l + 64 * ii], dt);
#pragma unroll
            for (int off = 1; off < 64; off <<= 1) dt += __shfl_xor(dt, off, 64);
            float dex = 2.f - 2.f * dt;
            if (kbest < 0 || dex < dbest || (dex == dbest && k < kbest)) { dbest = dex; kbest = k; }
        }
        if (l == 0) s_amin[r] = kbest;
    }
    __syncthreads();

    // q gather (CHW), 448B coalesced segments; overwrites the scratch slots
    int px = tid & 127, kg = tid >> 7;
    if (px < PPX) {
        const float* cr = codeN + (size_t)s_amin[px] * C_ + kg * 192;
        size_t qb = ((size_t)b * C_ + kg * 192) * HW_ + hw0 + px;
#pragma unroll 1
        for (int c4 = 0; c4 < 48; ++c4) {
            float4 v = *(const float4*)(cr + 4 * c4);
            qOut[qb + (size_t)(4 * c4 + 0) * HW_] = v.x;
            qOut[qb + (size_t)(4 * c4 + 1) * HW_] = v.y;
            qOut[qb + (size_t)(4 * c4 + 2) * HW_] = v.z;
            qOut[qb + (size_t)(4 * c4 + 3) * HW_] = v.w;
        }
    }
}

extern "C" void kernel_launch(void* const* d_in, const int* in_sizes, int n_in,
                              void* d_out, int out_size, void* d_ws, size_t ws_size,
                              hipStream_t stream) {
    const float* feat = (const float*)d_in[0];
    const float* cb   = (const float*)d_in[1];
    float* out    = (float*)d_out;
    float* f_out  = out + OFF_F;
    float* q_out  = out + OFF_Q;     // holds candidate scratch until k_q overwrites
    float* asg    = out + OFF_ASG;   // first 20.8 MB holds a_hi/b_hi until k_post
    float* dist   = out + OFF_DIST;

    float*  code_n = (float*)d_ws;                        // 3,145,728 B
    float*  inv_n  = (float*)((char*)d_ws + 3145728);     //   100,352 B
    float2* srow   = (float2*)((char*)d_ws + 3246080);    //   200,704 B

    u16* a_hi = (u16*)asg;
    u16* b_hi = a_hi + (size_t)N_ * C_;
    u32* Qi   = (u32*)q_out;

    k_code<<<K_ / 4, 256, 0, stream>>>(cb, code_n, b_hi);
    k_prep<<<dim3(HW_ / 16, B_), 256, 0, stream>>>(feat, f_out, inv_n, a_hi);
    k_gemm<<<dim3(K_ / 128, N_ / 128), 256, 0, stream>>>(a_hi, b_hi, dist);
    k_stats<<<N_ / 4, 256, 0, stream>>>(dist, srow);
    k_post<<<dim3(224, 4), 256, 0, stream>>>(dist, srow, Qi, asg);
    k_q<<<224, 256, 0, stream>>>(Qi, code_n, inv_n, f_out, q_out);
}

// Round 7
// 258.088 us; speedup vs baseline: 1.9051x; 1.1750x over previous
//
#include <hip/hip_runtime.h>

#define B_  32
#define C_  384
#define HW_ 784
#define N_  25088   // B_*HW_
#define K_  2048
#define PPX 112     // pixels per post/q block; 7*112=784

#define OFF_F    0
#define OFF_Q    9633792
#define OFF_ASG  19267584
#define OFF_DIST 70647808

#define MARGIN 0.02f

typedef unsigned short u16;
typedef unsigned int u32;
typedef __attribute__((ext_vector_type(8))) short short8;
typedef __attribute__((ext_vector_type(4))) float floatx4;
typedef __attribute__((ext_vector_type(4))) float f32x4;

static __device__ __forceinline__ u16 f2bf(float x) {
    u32 u = __builtin_bit_cast(u32, x);
    u32 r = (u + 0x7FFFu + ((u >> 16) & 1u)) >> 16;
    return (u16)r;
}

static __device__ __forceinline__ void gload_lds16(const void* g, void* l) {
    __builtin_amdgcn_global_load_lds(
        (const __attribute__((address_space(1))) unsigned int*)g,
        (__attribute__((address_space(3))) unsigned int*)l,
        16, 0, 0);
}

// candidate scratch in the q output region (overwritten by k_q's final gather):
// per (b, hw): slot s = chunk*17 -> count, s = chunk*17+1+ci -> candidate k
static __device__ __forceinline__ size_t qslot(int b, int s, int hw) {
    return ((size_t)b * C_ + s) * HW_ + hw;
}

// ---------------- K1: feat -> f, inv_n, a_hi  AND  codebook -> code_n, b_hi ----------------
// blocks 0..1567: prep tiles; blocks 1568..2079: codebook rows
__global__ __launch_bounds__(256) void k_prep(const float* __restrict__ feat,
                                              const float* __restrict__ cb,
                                              float* __restrict__ f_out,
                                              float* __restrict__ inv_n,
                                              u16* __restrict__ a_hi,
                                              float* __restrict__ code_n,
                                              u16* __restrict__ b_hi) {
    int tid = threadIdx.x;
    if (blockIdx.x >= 1568) {
        // ---- codebook path ----
        int row  = (blockIdx.x - 1568) * 4 + (tid >> 6);
        int lane = tid & 63;
        const float* src = cb + (size_t)row * C_;
        float v[6];
        float ss = 0.f;
#pragma unroll
        for (int i = 0; i < 6; ++i) { v[i] = src[lane + 64 * i]; ss += v[i] * v[i]; }
#pragma unroll
        for (int off = 32; off; off >>= 1) ss += __shfl_xor(ss, off, 64);
        float inv = 1.f / fmaxf(sqrtf(ss), 1e-12f);
#pragma unroll
        for (int i = 0; i < 6; ++i) {
            float vn = v[i] * inv;
            code_n[(size_t)row * C_ + lane + 64 * i] = vn;
            b_hi  [(size_t)row * C_ + lane + 64 * i] = f2bf(vn);
        }
        return;
    }
    // ---- feat path ----
    __shared__ float tile[C_][17];
    __shared__ float red[16][17];
    __shared__ float s_inv[16];
    int b   = blockIdx.x / 49;
    int hw0 = (blockIdx.x - b * 49) * 16;
    int px  = tid & 15, cq = tid >> 4;

#pragma unroll
    for (int it = 0; it < 24; ++it) {
        int c = cq + 16 * it;
        tile[c][px] = feat[((size_t)(b * C_ + c)) * HW_ + hw0 + px];
    }
    __syncthreads();
    float ss = 0.f;
#pragma unroll
    for (int q = 0; q < 24; ++q) {
        float v = tile[cq + 16 * q][px];
        ss = fmaf(v, v, ss);
    }
    red[cq][px] = ss;
    __syncthreads();
    if (tid < 16) {
        float tot = 0.f;
#pragma unroll
        for (int p = 0; p < 16; ++p) tot += red[p][tid];
        float inv = 1.f / fmaxf(sqrtf(tot), 1e-12f);
        s_inv[tid] = inv;
        inv_n[(size_t)b * HW_ + hw0 + tid] = inv;
    }
    __syncthreads();

    // f (N,C layout), nontemporal float4 stores
    {
        int p2 = tid >> 4, cc = tid & 15;
        float* fb = f_out + ((size_t)(b * HW_ + hw0 + p2)) * C_;
#pragma unroll
        for (int it = 0; it < 6; ++it) {
            int c0 = cc * 4 + 64 * it;
            f32x4 v;
            v[0] = tile[c0 + 0][p2];
            v[1] = tile[c0 + 1][p2];
            v[2] = tile[c0 + 2][p2];
            v[3] = tile[c0 + 3][p2];
            __builtin_nontemporal_store(v, (f32x4*)(fb + c0));
        }
    }
    // a_hi (normalized bf16, N,C contiguous, packed u32 writes) — re-read by GEMM, keep cached
    {
        int p2 = tid >> 4, cc = tid & 15;
        float inv = s_inv[p2];
        u16* aptr = a_hi + ((size_t)(b * HW_ + hw0 + p2)) * C_;
#pragma unroll
        for (int it = 0; it < 12; ++it) {
            int c0 = 2 * cc + 32 * it;
            u16 h0 = f2bf(tile[c0][p2] * inv);
            u16 h1 = f2bf(tile[c0 + 1][p2] * inv);
            *(u32*)(aptr + c0) = (u32)h0 | ((u32)h1 << 16);
        }
    }
}

// ---------------- K2: pure bf16 MFMA GEMM, dist = 2 - 2 * A.B^T ----------------
// 1-D grid of 3136 with bijective XCD swizzle: each XCD runs whole m-tile groups
__global__ __launch_bounds__(256) void k_gemm(const u16* __restrict__ A,
                                              const u16* __restrict__ Bm,
                                              float* __restrict__ D) {
    __shared__ u16 As[2][128 * 32];
    __shared__ u16 Bs[2][128 * 32];
    int tid = threadIdx.x;
    int lin = blockIdx.x;
    int swz = (lin & 7) * 392 + (lin >> 3);   // 3136 = 8 * 392, bijective
    int n0 = (swz & 15) * 128;
    int m0 = (swz >> 4) * 128;
    int w = tid >> 6, l = tid & 63;
    int wm = (w >> 1) * 64, wn = (w & 1) * 64;
    int q4 = l >> 4, r15 = l & 15;

    floatx4 acc[4][4];
#pragma unroll
    for (int i = 0; i < 4; ++i)
#pragma unroll
        for (int j = 0; j < 4; ++j) acc[i][j] = (floatx4)0.f;

    int srow = tid >> 2;
    int sp   = tid & 3;
    int fs   = (srow ^ (srow >> 2)) & 3;
    int kk0  = 8 * (sp ^ fs);

#define STAGE(buf, kt)                                                          \
    {                                                                           \
        _Pragma("unroll")                                                       \
        for (int q = 0; q < 2; ++q) {                                           \
            int row = q * 64 + srow;                                            \
            int off = (q * 256 + tid) * 16;                                     \
            gload_lds16(A  + (size_t)(m0 + row) * C_ + (kt) + kk0,              \
                        (char*)As[buf] + off);                                  \
            gload_lds16(Bm + (size_t)(n0 + row) * C_ + (kt) + kk0,              \
                        (char*)Bs[buf] + off);                                  \
        }                                                                       \
    }

    STAGE(0, 0);
    __syncthreads();

    const int slot = (q4 ^ ((r15 ^ (r15 >> 2)) & 3)) << 4;
#pragma unroll 1
    for (int t = 0; t < 12; ++t) {
        int cur = t & 1;
        if (t < 11) STAGE(cur ^ 1, (t + 1) * 32);
        const char* Ab = (const char*)As[cur];
        const char* Bb = (const char*)Bs[cur];
        short8 a[4], b[4];
#pragma unroll
        for (int i = 0; i < 4; ++i) {
            a[i] = *(const short8*)(Ab + (wm + i * 16 + r15) * 64 + slot);
            b[i] = *(const short8*)(Bb + (wn + i * 16 + r15) * 64 + slot);
        }
#pragma unroll
        for (int i = 0; i < 4; ++i)
#pragma unroll
            for (int j = 0; j < 4; ++j)
                acc[i][j] = __builtin_amdgcn_mfma_f32_16x16x32_bf16(a[i], b[j], acc[i][j], 0, 0, 0);
        __syncthreads();
    }

#pragma unroll
    for (int i = 0; i < 4; ++i) {
        int gm = m0 + wm + i * 16 + q4 * 4;
#pragma unroll
        for (int j = 0; j < 4; ++j) {
            int gn = n0 + wn + j * 16 + r15;
            float* p = D + (size_t)gm * K_ + gn;
#pragma unroll
            for (int r = 0; r < 4; ++r)
                p[(size_t)r * K_] = 2.f - 2.f * acc[i][j][r];
        }
    }
#undef STAGE
}

// ---------------- K3: streaming row stats: (inv, thr) per row ----------------
__global__ __launch_bounds__(256) void k_stats(const float* __restrict__ D,
                                               float2* __restrict__ srow) {
    int row = blockIdx.x * 4 + (threadIdx.x >> 6);
    int l   = threadIdx.x & 63;
    const float* dr = D + (size_t)row * K_;
    float es = 0.f, dm = 3.4e38f;
#pragma unroll
    for (int i = 0; i < 8; ++i) {
        float4 v = *(const float4*)(dr + l * 4 + 256 * i);
        es += __expf(-10.f * v.x) + __expf(-10.f * v.y)
            + __expf(-10.f * v.z) + __expf(-10.f * v.w);
        dm = fminf(dm, fminf(fminf(v.x, v.y), fminf(v.z, v.w)));
    }
#pragma unroll
    for (int off = 32; off; off >>= 1) {
        es += __shfl_xor(es, off, 64);
        dm = fminf(dm, __shfl_xor(dm, off, 64));
    }
    if (l == 0) {
        float2 st;
        st.x = 1.f / es;
        st.y = dm + MARGIN;
        srow[row] = st;
    }
}

// ---------------- K4: assignment + candidate collection ----------------
// grid (224 hw-tiles, 4 k-chunks of 512); NT dist loads, NT asg stores
__global__ __launch_bounds__(256) void k_post(const float* __restrict__ D,
                                              const float2* __restrict__ srow,
                                              u32* __restrict__ Qi,
                                              float* __restrict__ asg) {
    __shared__ float tbuf[64][113];
    __shared__ float s_inv[PPX], s_thr[PPX];
    __shared__ int   s_cnt[PPX];
    __shared__ int   s_cand[PPX][16];
    int tile = blockIdx.x;
    int kc   = blockIdx.y;
    int b    = tile / 7;
    int hw0  = (tile - b * 7) * PPX;
    int n0   = b * HW_ + hw0;
    int tid  = threadIdx.x;

    if (tid < PPX) {
        float2 st = srow[n0 + tid];
        s_inv[tid] = st.x;
        s_thr[tid] = st.y;
        s_cnt[tid] = 0;
    }
    __syncthreads();

    int r16 = tid >> 4, c4 = (tid & 15) * 4;
    int px = tid & 127, kg = tid >> 7;
#pragma unroll 1
    for (int ch = 0; ch < 8; ++ch) {
        int k0 = kc * 512 + ch * 64;
#pragma unroll
        for (int rr = 0; rr < 7; ++rr) {
            int row = r16 + 16 * rr;
            f32x4 dv = __builtin_nontemporal_load(
                (const f32x4*)(D + (size_t)(n0 + row) * K_ + k0 + c4));
            float inv = s_inv[row], thr = s_thr[row];
#pragma unroll
            for (int cc = 0; cc < 4; ++cc) {
                float d = dv[cc];
                tbuf[c4 + cc][row] = __expf(-10.f * d) * inv;
                if (d <= thr) {
                    int idx = atomicAdd(&s_cnt[row], 1);
                    if (idx < 16) s_cand[row][idx] = k0 + c4 + cc;
                }
            }
        }
        __syncthreads();
        if (px < PPX) {
            size_t base = ((size_t)(b * K_ + k0 + kg * 32)) * HW_ + hw0 + px;
#pragma unroll
            for (int ki = 0; ki < 32; ++ki)
                __builtin_nontemporal_store(tbuf[kg * 32 + ki][px],
                                            asg + base + (size_t)ki * HW_);
        }
        __syncthreads();
    }

    // dump candidate lists for this k-chunk
    if (tid < PPX) {
        int cnt = s_cnt[tid];
        cnt = cnt > 16 ? 16 : cnt;
        Qi[qslot(b, kc * 17, hw0 + tid)] = (u32)cnt;
        for (int ci = 0; ci < cnt; ++ci)
            Qi[qslot(b, kc * 17 + 1 + ci, hw0 + tid)] = (u32)s_cand[tid][ci];
    }
}

// ---------------- K5: merge candidates, exact recheck, q gather ----------------
__global__ __launch_bounds__(256) void k_q(const u32* __restrict__ Qi,
                                           const float* __restrict__ codeN,
                                           const float* __restrict__ invN,
                                           const float* __restrict__ f_in,
                                           float* __restrict__ qOut) {
    __shared__ int s_amin[PPX], s_cnt[PPX];
    __shared__ int s_cand[PPX][64];
    int tile = blockIdx.x;
    int b    = tile / 7;
    int hw0  = (tile - b * 7) * PPX;
    int npix = b * HW_ + hw0;
    int tid  = threadIdx.x;

    if (tid < PPX) {
        int total = 0;
#pragma unroll
        for (int kc = 0; kc < 4; ++kc) {
            int cnt = (int)Qi[qslot(b, kc * 17, hw0 + tid)];
            for (int ci = 0; ci < cnt; ++ci)
                s_cand[tid][total++] = (int)Qi[qslot(b, kc * 17 + 1 + ci, hw0 + tid)];
        }
        s_cnt[tid]  = total;
        s_amin[tid] = s_cand[tid][0];
    }
    __syncthreads();

    // exact fp32 recheck, one wave per ambiguous row
    int w = tid >> 6, l = tid & 63;
#pragma unroll 1
    for (int r = w; r < PPX; r += 4) {
        int cnt = s_cnt[r];
        if (cnt < 2) continue;
        float ivn = invN[npix + r];
        float fv[6];
        const float* frow = f_in + (size_t)(npix + r) * C_;
#pragma unroll
        for (int ii = 0; ii < 6; ++ii)
            fv[ii] = frow[l + 64 * ii] * ivn;
        float dbest = 3.4e38f;
        int   kbest = -1;
        for (int ci = 0; ci < cnt; ++ci) {
            int k = s_cand[r][ci];
            float dt = 0.f;
            const float* cr = codeN + (size_t)k * C_;
#pragma unroll
            for (int ii = 0; ii < 6; ++ii) dt = fmaf(fv[ii], cr[l + 64 * ii], dt);
#pragma unroll
            for (int off = 1; off < 64; off <<= 1) dt += __shfl_xor(dt, off, 64);
            float dex = 2.f - 2.f * dt;
            if (kbest < 0 || dex < dbest || (dex == dbest && k < kbest)) { dbest = dex; kbest = k; }
        }
        if (l == 0) s_amin[r] = kbest;
    }
    __syncthreads();

    // q gather (CHW), 448B coalesced segments, NT stores; overwrites scratch slots
    int px = tid & 127, kg = tid >> 7;
    if (px < PPX) {
        const float* cr = codeN + (size_t)s_amin[px] * C_ + kg * 192;
        size_t qb = ((size_t)b * C_ + kg * 192) * HW_ + hw0 + px;
#pragma unroll 1
        for (int c4 = 0; c4 < 48; ++c4) {
            float4 v = *(const float4*)(cr + 4 * c4);
            __builtin_nontemporal_store(v.x, qOut + qb + (size_t)(4 * c4 + 0) * HW_);
            __builtin_nontemporal_store(v.y, qOut + qb + (size_t)(4 * c4 + 1) * HW_);
            __builtin_nontemporal_store(v.z, qOut + qb + (size_t)(4 * c4 + 2) * HW_);
            __builtin_nontemporal_store(v.w, qOut + qb + (size_t)(4 * c4 + 3) * HW_);
        }
    }
}

extern "C" void kernel_launch(void* const* d_in, const int* in_sizes, int n_in,
                              void* d_out, int out_size, void* d_ws, size_t ws_size,
                              hipStream_t stream) {
    const float* feat = (const float*)d_in[0];
    const float* cb   = (const float*)d_in[1];
    float* out    = (float*)d_out;
    float* f_out  = out + OFF_F;
    float* q_out  = out + OFF_Q;     // holds candidate scratch until k_q overwrites
    float* asg    = out + OFF_ASG;   // first 20.8 MB holds a_hi/b_hi until k_post
    float* dist   = out + OFF_DIST;

    float*  code_n = (float*)d_ws;                        // 3,145,728 B
    float*  inv_n  = (float*)((char*)d_ws + 3145728);     //   100,352 B
    float2* srow   = (float2*)((char*)d_ws + 3246080);    //   200,704 B

    u16* a_hi = (u16*)asg;
    u16* b_hi = a_hi + (size_t)N_ * C_;
    u32* Qi   = (u32*)q_out;

    k_prep<<<2080, 256, 0, stream>>>(feat, cb, f_out, inv_n, a_hi, code_n, b_hi);
    k_gemm<<<3136, 256, 0, stream>>>(a_hi, b_hi, dist);
    k_stats<<<N_ / 4, 256, 0, stream>>>(dist, srow);
    k_post<<<dim3(224, 4), 256, 0, stream>>>(dist, srow, Qi, asg);
    k_q<<<224, 256, 0, stream>>>(Qi, code_n, inv_n, f_out, q_out);
}

// Round 8
// 246.918 us; speedup vs baseline: 1.9912x; 1.0452x over previous
//
#include <hip/hip_runtime.h>

#define B_  32
#define C_  384
#define HW_ 784
#define N_  25088   // B_*HW_
#define K_  2048
#define PPX 112     // pixels per post/q block; 7*112=784

#define OFF_F    0
#define OFF_Q    9633792
#define OFF_ASG  19267584
#define OFF_DIST 70647808

#define MARGIN 0.02f

typedef unsigned short u16;
typedef unsigned int u32;
typedef __attribute__((ext_vector_type(8))) short short8;
typedef __attribute__((ext_vector_type(4))) float floatx4;
typedef __attribute__((ext_vector_type(4))) float f32x4;
typedef __attribute__((ext_vector_type(4))) u16 u16x4;
typedef __attribute__((ext_vector_type(8))) u16 u16x8;

static __device__ __forceinline__ u16 f2bf(float x) {
    u32 u = __builtin_bit_cast(u32, x);
    u32 r = (u + 0x7FFFu + ((u >> 16) & 1u)) >> 16;
    return (u16)r;
}
static __device__ __forceinline__ float bf2f(u16 v) {
    return __builtin_bit_cast(float, (u32)v << 16);
}

static __device__ __forceinline__ void gload_lds16(const void* g, void* l) {
    __builtin_amdgcn_global_load_lds(
        (const __attribute__((address_space(1))) unsigned int*)g,
        (__attribute__((address_space(3))) unsigned int*)l,
        16, 0, 0);
}

// candidate scratch in the q output region (overwritten by k_q's final gather):
// per (b, hw): slot s = chunk*17 -> count, s = chunk*17+1+ci -> candidate k
static __device__ __forceinline__ size_t qslot(int b, int s, int hw) {
    return ((size_t)b * C_ + s) * HW_ + hw;
}

// ---------------- K1: feat -> f, inv_n, a_hi  AND  codebook -> code_n, b_hi ----------------
__global__ __launch_bounds__(256) void k_prep(const float* __restrict__ feat,
                                              const float* __restrict__ cb,
                                              float* __restrict__ f_out,
                                              float* __restrict__ inv_n,
                                              u16* __restrict__ a_hi,
                                              float* __restrict__ code_n,
                                              u16* __restrict__ b_hi) {
    int tid = threadIdx.x;
    if (blockIdx.x >= 1568) {
        int row  = (blockIdx.x - 1568) * 4 + (tid >> 6);
        int lane = tid & 63;
        const float* src = cb + (size_t)row * C_;
        float v[6];
        float ss = 0.f;
#pragma unroll
        for (int i = 0; i < 6; ++i) { v[i] = src[lane + 64 * i]; ss += v[i] * v[i]; }
#pragma unroll
        for (int off = 32; off; off >>= 1) ss += __shfl_xor(ss, off, 64);
        float inv = 1.f / fmaxf(sqrtf(ss), 1e-12f);
#pragma unroll
        for (int i = 0; i < 6; ++i) {
            float vn = v[i] * inv;
            code_n[(size_t)row * C_ + lane + 64 * i] = vn;
            b_hi  [(size_t)row * C_ + lane + 64 * i] = f2bf(vn);
        }
        return;
    }
    __shared__ float tile[C_][17];
    __shared__ float red[16][17];
    __shared__ float s_inv[16];
    int b   = blockIdx.x / 49;
    int hw0 = (blockIdx.x - b * 49) * 16;
    int px  = tid & 15, cq = tid >> 4;

#pragma unroll
    for (int it = 0; it < 24; ++it) {
        int c = cq + 16 * it;
        tile[c][px] = feat[((size_t)(b * C_ + c)) * HW_ + hw0 + px];
    }
    __syncthreads();
    float ss = 0.f;
#pragma unroll
    for (int q = 0; q < 24; ++q) {
        float v = tile[cq + 16 * q][px];
        ss = fmaf(v, v, ss);
    }
    red[cq][px] = ss;
    __syncthreads();
    if (tid < 16) {
        float tot = 0.f;
#pragma unroll
        for (int p = 0; p < 16; ++p) tot += red[p][tid];
        float inv = 1.f / fmaxf(sqrtf(tot), 1e-12f);
        s_inv[tid] = inv;
        inv_n[(size_t)b * HW_ + hw0 + tid] = inv;
    }
    __syncthreads();

    {
        int p2 = tid >> 4, cc = tid & 15;
        float* fb = f_out + ((size_t)(b * HW_ + hw0 + p2)) * C_;
#pragma unroll
        for (int it = 0; it < 6; ++it) {
            int c0 = cc * 4 + 64 * it;
            f32x4 v;
            v[0] = tile[c0 + 0][p2];
            v[1] = tile[c0 + 1][p2];
            v[2] = tile[c0 + 2][p2];
            v[3] = tile[c0 + 3][p2];
            __builtin_nontemporal_store(v, (f32x4*)(fb + c0));
        }
    }
    {
        int p2 = tid >> 4, cc = tid & 15;
        float inv = s_inv[p2];
        u16* aptr = a_hi + ((size_t)(b * HW_ + hw0 + p2)) * C_;
#pragma unroll
        for (int it = 0; it < 12; ++it) {
            int c0 = 2 * cc + 32 * it;
            u16 h0 = f2bf(tile[c0][p2] * inv);
            u16 h1 = f2bf(tile[c0 + 1][p2] * inv);
            *(u32*)(aptr + c0) = (u32)h0 | ((u32)h1 << 16);
        }
    }
}

// ---------------- K2: bf16 MFMA GEMM; DB: also write bf16 dist shadow, NT fp32 dist ----------------
template <bool DB>
__global__ __launch_bounds__(256) void k_gemm(const u16* __restrict__ A,
                                              const u16* __restrict__ Bm,
                                              float* __restrict__ D,
                                              u16* __restrict__ db) {
    __shared__ u16 As[2][128 * 32];
    __shared__ u16 Bs[2][128 * 32];
    int tid = threadIdx.x;
    int lin = blockIdx.x;
    int swz = (lin & 7) * 392 + (lin >> 3);   // 3136 = 8 * 392, bijective
    int n0 = (swz & 15) * 128;
    int m0 = (swz >> 4) * 128;
    int w = tid >> 6, l = tid & 63;
    int wm = (w >> 1) * 64, wn = (w & 1) * 64;
    int q4 = l >> 4, r15 = l & 15;

    floatx4 acc[4][4];
#pragma unroll
    for (int i = 0; i < 4; ++i)
#pragma unroll
        for (int j = 0; j < 4; ++j) acc[i][j] = (floatx4)0.f;

    int srow = tid >> 2;
    int sp   = tid & 3;
    int fs   = (srow ^ (srow >> 2)) & 3;
    int kk0  = 8 * (sp ^ fs);

#define STAGE(buf, kt)                                                          \
    {                                                                           \
        _Pragma("unroll")                                                       \
        for (int q = 0; q < 2; ++q) {                                           \
            int row = q * 64 + srow;                                            \
            int off = (q * 256 + tid) * 16;                                     \
            gload_lds16(A  + (size_t)(m0 + row) * C_ + (kt) + kk0,              \
                        (char*)As[buf] + off);                                  \
            gload_lds16(Bm + (size_t)(n0 + row) * C_ + (kt) + kk0,              \
                        (char*)Bs[buf] + off);                                  \
        }                                                                       \
    }

    STAGE(0, 0);
    __syncthreads();

    const int slot = (q4 ^ ((r15 ^ (r15 >> 2)) & 3)) << 4;
#pragma unroll 1
    for (int t = 0; t < 12; ++t) {
        int cur = t & 1;
        if (t < 11) STAGE(cur ^ 1, (t + 1) * 32);
        const char* Ab = (const char*)As[cur];
        const char* Bb = (const char*)Bs[cur];
        short8 a[4], b[4];
#pragma unroll
        for (int i = 0; i < 4; ++i) {
            a[i] = *(const short8*)(Ab + (wm + i * 16 + r15) * 64 + slot);
            b[i] = *(const short8*)(Bb + (wn + i * 16 + r15) * 64 + slot);
        }
#pragma unroll
        for (int i = 0; i < 4; ++i)
#pragma unroll
            for (int j = 0; j < 4; ++j)
                acc[i][j] = __builtin_amdgcn_mfma_f32_16x16x32_bf16(a[i], b[j], acc[i][j], 0, 0, 0);
        __syncthreads();
    }

#pragma unroll
    for (int i = 0; i < 4; ++i) {
        int gm = m0 + wm + i * 16 + q4 * 4;
#pragma unroll
        for (int j = 0; j < 4; ++j) {
            int gn = n0 + wn + j * 16 + r15;
#pragma unroll
            for (int r = 0; r < 4; ++r) {
                float d = 2.f - 2.f * acc[i][j][r];
                if (DB) {
                    __builtin_nontemporal_store(d, D + (size_t)(gm + r) * K_ + gn);
                    db[(size_t)(gm + r) * K_ + gn] = f2bf(d);
                } else {
                    D[(size_t)(gm + r) * K_ + gn] = d;
                }
            }
        }
    }
#undef STAGE
}

// ---------------- K3: streaming row stats from bf16 shadow ----------------
__global__ __launch_bounds__(256) void k_stats_b(const u16* __restrict__ db,
                                                 float2* __restrict__ srow) {
    int row = blockIdx.x * 4 + (threadIdx.x >> 6);
    int l   = threadIdx.x & 63;
    const u16* dr = db + (size_t)row * K_;
    float es = 0.f, dm = 3.4e38f;
#pragma unroll
    for (int i = 0; i < 4; ++i) {
        u16x8 v = *(const u16x8*)(dr + l * 8 + 512 * i);
#pragma unroll
        for (int e = 0; e < 8; ++e) {
            float d = bf2f(v[e]);
            es += __expf(-10.f * d);
            dm = fminf(dm, d);
        }
    }
#pragma unroll
    for (int off = 32; off; off >>= 1) {
        es += __shfl_xor(es, off, 64);
        dm = fminf(dm, __shfl_xor(dm, off, 64));
    }
    if (l == 0) {
        float2 st;
        st.x = 1.f / es;
        st.y = dm + MARGIN;
        srow[row] = st;
    }
}

// fp32 fallback
__global__ __launch_bounds__(256) void k_stats_f(const float* __restrict__ D,
                                                 float2* __restrict__ srow) {
    int row = blockIdx.x * 4 + (threadIdx.x >> 6);
    int l   = threadIdx.x & 63;
    const float* dr = D + (size_t)row * K_;
    float es = 0.f, dm = 3.4e38f;
#pragma unroll
    for (int i = 0; i < 8; ++i) {
        float4 v = *(const float4*)(dr + l * 4 + 256 * i);
        es += __expf(-10.f * v.x) + __expf(-10.f * v.y)
            + __expf(-10.f * v.z) + __expf(-10.f * v.w);
        dm = fminf(dm, fminf(fminf(v.x, v.y), fminf(v.z, v.w)));
    }
#pragma unroll
    for (int off = 32; off; off >>= 1) {
        es += __shfl_xor(es, off, 64);
        dm = fminf(dm, __shfl_xor(dm, off, 64));
    }
    if (l == 0) {
        float2 st;
        st.x = 1.f / es;
        st.y = dm + MARGIN;
        srow[row] = st;
    }
}

// ---------------- K4: assignment + candidate collection (bf16 shadow read) ----------------
__global__ __launch_bounds__(256) void k_post_b(const u16* __restrict__ db,
                                                const float2* __restrict__ srow,
                                                u32* __restrict__ Qi,
                                                float* __restrict__ asg) {
    __shared__ float tbuf[64][113];
    __shared__ float s_inv[PPX], s_thr[PPX];
    __shared__ int   s_cnt[PPX];
    __shared__ int   s_cand[PPX][16];
    int tile = blockIdx.x;
    int kc   = blockIdx.y;
    int b    = tile / 7;
    int hw0  = (tile - b * 7) * PPX;
    int n0   = b * HW_ + hw0;
    int tid  = threadIdx.x;

    if (tid < PPX) {
        float2 st = srow[n0 + tid];
        s_inv[tid] = st.x;
        s_thr[tid] = st.y;
        s_cnt[tid] = 0;
    }
    __syncthreads();

    int r16 = tid >> 4, c4 = (tid & 15) * 4;
    int px = tid & 127, kg = tid >> 7;
#pragma unroll 1
    for (int ch = 0; ch < 8; ++ch) {
        int k0 = kc * 512 + ch * 64;
#pragma unroll
        for (int rr = 0; rr < 7; ++rr) {
            int row = r16 + 16 * rr;
            u16x4 dv = *(const u16x4*)(db + (size_t)(n0 + row) * K_ + k0 + c4);
            float inv = s_inv[row], thr = s_thr[row];
#pragma unroll
            for (int cc = 0; cc < 4; ++cc) {
                float d = bf2f(dv[cc]);
                tbuf[c4 + cc][row] = __expf(-10.f * d) * inv;
                if (d <= thr) {
                    int idx = atomicAdd(&s_cnt[row], 1);
                    if (idx < 16) s_cand[row][idx] = k0 + c4 + cc;
                }
            }
        }
        __syncthreads();
        if (px < PPX) {
            size_t base = ((size_t)(b * K_ + k0 + kg * 32)) * HW_ + hw0 + px;
#pragma unroll
            for (int ki = 0; ki < 32; ++ki)
                __builtin_nontemporal_store(tbuf[kg * 32 + ki][px],
                                            asg + base + (size_t)ki * HW_);
        }
        __syncthreads();
    }

    if (tid < PPX) {
        int cnt = s_cnt[tid];
        cnt = cnt > 16 ? 16 : cnt;
        Qi[qslot(b, kc * 17, hw0 + tid)] = (u32)cnt;
        for (int ci = 0; ci < cnt; ++ci)
            Qi[qslot(b, kc * 17 + 1 + ci, hw0 + tid)] = (u32)s_cand[tid][ci];
    }
}

// fp32 fallback
__global__ __launch_bounds__(256) void k_post_f(const float* __restrict__ D,
                                                const float2* __restrict__ srow,
                                                u32* __restrict__ Qi,
                                                float* __restrict__ asg) {
    __shared__ float tbuf[64][113];
    __shared__ float s_inv[PPX], s_thr[PPX];
    __shared__ int   s_cnt[PPX];
    __shared__ int   s_cand[PPX][16];
    int tile = blockIdx.x;
    int kc   = blockIdx.y;
    int b    = tile / 7;
    int hw0  = (tile - b * 7) * PPX;
    int n0   = b * HW_ + hw0;
    int tid  = threadIdx.x;

    if (tid < PPX) {
        float2 st = srow[n0 + tid];
        s_inv[tid] = st.x;
        s_thr[tid] = st.y;
        s_cnt[tid] = 0;
    }
    __syncthreads();

    int r16 = tid >> 4, c4 = (tid & 15) * 4;
    int px = tid & 127, kg = tid >> 7;
#pragma unroll 1
    for (int ch = 0; ch < 8; ++ch) {
        int k0 = kc * 512 + ch * 64;
#pragma unroll
        for (int rr = 0; rr < 7; ++rr) {
            int row = r16 + 16 * rr;
            f32x4 dv = __builtin_nontemporal_load(
                (const f32x4*)(D + (size_t)(n0 + row) * K_ + k0 + c4));
            float inv = s_inv[row], thr = s_thr[row];
#pragma unroll
            for (int cc = 0; cc < 4; ++cc) {
                float d = dv[cc];
                tbuf[c4 + cc][row] = __expf(-10.f * d) * inv;
                if (d <= thr) {
                    int idx = atomicAdd(&s_cnt[row], 1);
                    if (idx < 16) s_cand[row][idx] = k0 + c4 + cc;
                }
            }
        }
        __syncthreads();
        if (px < PPX) {
            size_t base = ((size_t)(b * K_ + k0 + kg * 32)) * HW_ + hw0 + px;
#pragma unroll
            for (int ki = 0; ki < 32; ++ki)
                __builtin_nontemporal_store(tbuf[kg * 32 + ki][px],
                                            asg + base + (size_t)ki * HW_);
        }
        __syncthreads();
    }

    if (tid < PPX) {
        int cnt = s_cnt[tid];
        cnt = cnt > 16 ? 16 : cnt;
        Qi[qslot(b, kc * 17, hw0 + tid)] = (u32)cnt;
        for (int ci = 0; ci < cnt; ++ci)
            Qi[qslot(b, kc * 17 + 1 + ci, hw0 + tid)] = (u32)s_cand[tid][ci];
    }
}

// ---------------- K5: merge candidates, exact recheck, q gather ----------------
__global__ __launch_bounds__(256) void k_q(const u32* __restrict__ Qi,
                                           const float* __restrict__ codeN,
                                           const float* __restrict__ invN,
                                           const float* __restrict__ f_in,
                                           float* __restrict__ qOut) {
    __shared__ int s_amin[PPX], s_cnt[PPX];
    __shared__ int s_cand[PPX][64];
    int tile = blockIdx.x;
    int b    = tile / 7;
    int hw0  = (tile - b * 7) * PPX;
    int npix = b * HW_ + hw0;
    int tid  = threadIdx.x;

    if (tid < PPX) {
        int total = 0;
#pragma unroll
        for (int kc = 0; kc < 4; ++kc) {
            int cnt = (int)Qi[qslot(b, kc * 17, hw0 + tid)];
            for (int ci = 0; ci < cnt; ++ci)
                s_cand[tid][total++] = (int)Qi[qslot(b, kc * 17 + 1 + ci, hw0 + tid)];
        }
        s_cnt[tid]  = total;
        s_amin[tid] = s_cand[tid][0];
    }
    __syncthreads();

    int w = tid >> 6, l = tid & 63;
#pragma unroll 1
    for (int r = w; r < PPX; r += 4) {
        int cnt = s_cnt[r];
        if (cnt < 2) continue;
        float ivn = invN[npix + r];
        float fv[6];
        const float* frow = f_in + (size_t)(npix + r) * C_;
#pragma unroll
        for (int ii = 0; ii < 6; ++ii)
            fv[ii] = frow[l + 64 * ii] * ivn;
        float dbest = 3.4e38f;
        int   kbest = -1;
        for (int ci = 0; ci < cnt; ++ci) {
            int k = s_cand[r][ci];
            float dt = 0.f;
            const float* cr = codeN + (size_t)k * C_;
#pragma unroll
            for (int ii = 0; ii < 6; ++ii) dt = fmaf(fv[ii], cr[l + 64 * ii], dt);
#pragma unroll
            for (int off = 1; off < 64; off <<= 1) dt += __shfl_xor(dt, off, 64);
            float dex = 2.f - 2.f * dt;
            if (kbest < 0 || dex < dbest || (dex == dbest && k < kbest)) { dbest = dex; kbest = k; }
        }
        if (l == 0) s_amin[r] = kbest;
    }
    __syncthreads();

    int px = tid & 127, kg = tid >> 7;
    if (px < PPX) {
        const float* cr = codeN + (size_t)s_amin[px] * C_ + kg * 192;
        size_t qb = ((size_t)b * C_ + kg * 192) * HW_ + hw0 + px;
#pragma unroll 1
        for (int c4 = 0; c4 < 48; ++c4) {
            float4 v = *(const float4*)(cr + 4 * c4);
            __builtin_nontemporal_store(v.x, qOut + qb + (size_t)(4 * c4 + 0) * HW_);
            __builtin_nontemporal_store(v.y, qOut + qb + (size_t)(4 * c4 + 1) * HW_);
            __builtin_nontemporal_store(v.z, qOut + qb + (size_t)(4 * c4 + 2) * HW_);
            __builtin_nontemporal_store(v.w, qOut + qb + (size_t)(4 * c4 + 3) * HW_);
        }
    }
}

extern "C" void kernel_launch(void* const* d_in, const int* in_sizes, int n_in,
                              void* d_out, int out_size, void* d_ws, size_t ws_size,
                              hipStream_t stream) {
    const float* feat = (const float*)d_in[0];
    const float* cb   = (const float*)d_in[1];
    float* out    = (float*)d_out;
    float* f_out  = out + OFF_F;
    float* q_out  = out + OFF_Q;     // holds candidate scratch until k_q overwrites
    float* asg    = out + OFF_ASG;   // first 20.8 MB holds a_hi/b_hi until k_post
    float* dist   = out + OFF_DIST;

    u16* a_hi = (u16*)asg;
    u16* b_hi = a_hi + (size_t)N_ * C_;
    u32* Qi   = (u32*)q_out;

    const size_t DB_BYTES = (size_t)N_ * K_ * 2;          // 102,760,448
    bool big = ws_size >= DB_BYTES + 3145728 + 100352 + 200704;

    if (big) {
        u16*    db     = (u16*)d_ws;
        float*  code_n = (float*)((char*)d_ws + DB_BYTES);
        float*  inv_n  = (float*)((char*)d_ws + DB_BYTES + 3145728);
        float2* srow   = (float2*)((char*)d_ws + DB_BYTES + 3145728 + 100352);

        k_prep<<<2080, 256, 0, stream>>>(feat, cb, f_out, inv_n, a_hi, code_n, b_hi);
        k_gemm<true><<<3136, 256, 0, stream>>>(a_hi, b_hi, dist, db);
        k_stats_b<<<N_ / 4, 256, 0, stream>>>(db, srow);
        k_post_b<<<dim3(224, 4), 256, 0, stream>>>(db, srow, Qi, asg);
        k_q<<<224, 256, 0, stream>>>(Qi, code_n, inv_n, f_out, q_out);
    } else {
        float*  code_n = (float*)d_ws;
        float*  inv_n  = (float*)((char*)d_ws + 3145728);
        float2* srow   = (float2*)((char*)d_ws + 3246080);

        k_prep<<<2080, 256, 0, stream>>>(feat, cb, f_out, inv_n, a_hi, code_n, b_hi);
        k_gemm<false><<<3136, 256, 0, stream>>>(a_hi, b_hi, dist, nullptr);
        k_stats_f<<<N_ / 4, 256, 0, stream>>>(dist, srow);
        k_post_f<<<dim3(224, 4), 256, 0, stream>>>(dist, srow, Qi, asg);
        k_q<<<224, 256, 0, stream>>>(Qi, code_n, inv_n, f_out, q_out);
    }
}